// Round 1
// baseline (855.781 us; speedup 1.0000x reference)
//
#include <hip/hip_runtime.h>
#include <hip/hip_bf16.h>

// MPNN on MI355X.
// Key identity: sum_e relu(a[dst]+b[src]) @ w2 == (sum_e relu(a[dst]+b[src])) @ w2
// -> per-edge work is only gather+add+relu+accumulate; all GEMMs are per-node.
// a = h@w1[:128] + b1, b = h@w1[128:].  b2 enters as (indeg+1)*b2 per node.
// All intermediates bf16 (absmax threshold is bf16-grade 0.26).

typedef __bf16 bf16_t;
typedef bf16_t bf16x8 __attribute__((ext_vector_type(8)));
typedef float f32x4 __attribute__((ext_vector_type(4)));
typedef unsigned int u32;
typedef unsigned short u16;

__device__ __forceinline__ float bflo(u32 v) { return __builtin_bit_cast(float, v << 16); }
__device__ __forceinline__ float bfhi(u32 v) { return __builtin_bit_cast(float, v & 0xffff0000u); }
__device__ __forceinline__ u32 bfpack(float x, float y) {
    u16 a = __builtin_bit_cast(u16, (bf16_t)x);
    u16 b = __builtin_bit_cast(u16, (bf16_t)y);
    return (u32)a | ((u32)b << 16);
}

// ---------------- prep: fp32 x -> bf16 ----------------
__global__ __launch_bounds__(256) void convx_kernel(const float* __restrict__ x,
                                                    bf16_t* __restrict__ xb, int total) {
    int i = (blockIdx.x * 256 + threadIdx.x) * 4;
    if (i >= total) return;
    float4 v = *(const float4*)(x + i);
    u32 o0 = bfpack(v.x, v.y), o1 = bfpack(v.z, v.w);
    *(uint2*)(xb + i) = make_uint2(o0, o1);
}

// ---------------- prep: weights -> transposed bf16 (one launch per layer) ----------------
// W1t[j][k] = lin_w[k][j]            (128x128)
// W12t[j][k]: j<128 -> w1[k][j] ; j>=128 -> w1[128+k][j-128]   (256x128)
// W2t[j][k] = w2[k][j]               (128x128)
// bias256 = [b1, zeros(128)]
__global__ __launch_bounds__(256) void prepw_kernel(const float* __restrict__ lin_w,
                                                    const float* __restrict__ w1,
                                                    const float* __restrict__ w2,
                                                    const float* __restrict__ b1,
                                                    bf16_t* __restrict__ W1t,
                                                    bf16_t* __restrict__ W12t,
                                                    bf16_t* __restrict__ W2t,
                                                    float* __restrict__ bias256) {
    int idx = blockIdx.x * 256 + threadIdx.x;
    if (idx < 16384) {
        int j = idx >> 7, k = idx & 127;
        W1t[idx] = (bf16_t)lin_w[k * 128 + j];
    } else if (idx < 16384 + 32768) {
        int i = idx - 16384;
        int j = i >> 7, k = i & 127;
        float v = (j < 128) ? w1[k * 128 + j] : w1[(128 + k) * 128 + (j - 128)];
        W12t[i] = (bf16_t)v;
    } else if (idx < 16384 + 32768 + 16384) {
        int i = idx - 49152;
        int j = i >> 7, k = i & 127;
        W2t[i] = (bf16_t)w2[k * 128 + j];
    } else if (idx < 65792) {
        int i = idx - 65536;
        bias256[i] = (i < 128) ? b1[i] : 0.f;
    }
}

// ---------------- CSR build ----------------
__global__ __launch_bounds__(256) void deg_kernel(const int* __restrict__ ei,
                                                  int* __restrict__ deg, int E) {
    int e = blockIdx.x * 256 + threadIdx.x;
    if (e < E) atomicAdd(&deg[ei[E + e]], 1);  // dst = ei[1][e]
}

__global__ __launch_bounds__(1024) void scan_kernel(const int* __restrict__ deg,
                                                    int* __restrict__ row_ptr,
                                                    float* __restrict__ cntp1f, int N) {
    __shared__ int part[1024];
    int t = threadIdx.x;
    const int C = (N + 1023) / 1024;
    int base = t * C;
    int s = 0;
    for (int i = 0; i < C; ++i) {
        int idx = base + i;
        if (idx < N) s += deg[idx];
    }
    part[t] = s;
    __syncthreads();
    for (int off = 1; off < 1024; off <<= 1) {
        int v = (t >= off) ? part[t - off] : 0;
        __syncthreads();
        part[t] += v;
        __syncthreads();
    }
    int run = part[t] - s;  // exclusive prefix
    for (int i = 0; i < C; ++i) {
        int idx = base + i;
        if (idx < N) {
            int d = deg[idx];
            row_ptr[idx] = run;
            run += d;
            cntp1f[idx] = (float)(d + 1);
        }
    }
    if (t == 1023) row_ptr[N] = run;
}

__global__ __launch_bounds__(256) void scatter_kernel(const int* __restrict__ ei,
                                                      const int* __restrict__ row_ptr,
                                                      int* __restrict__ cursor,
                                                      int* __restrict__ colarr, int E) {
    int e = blockIdx.x * 256 + threadIdx.x;
    if (e >= E) return;
    int d = ei[E + e], s = ei[e];
    int pos = row_ptr[d] + atomicAdd(&cursor[d], 1);
    colarr[pos] = s;
}

// ---------------- node GEMM: Y[N,ldc slice] = X[N,128] @ W + bias (MFMA bf16) ----------------
// Wt is [ncol_total,128] (transposed, k contiguous). blockIdx.y selects a 128-col slice.
// epilogue: v = acc + bias[col] + rowscale[r]*bias2[col]; optional relu; bf16 store.
__global__ __launch_bounds__(256) void gemm_node(const bf16_t* __restrict__ X,
                                                 const bf16_t* __restrict__ Wt,
                                                 const float* __restrict__ bias,
                                                 const float* __restrict__ bias2,
                                                 const float* __restrict__ rowscale,
                                                 bf16_t* __restrict__ Y, int N, int ldc,
                                                 int relu_flag) {
    const int coloff = blockIdx.y * 128;
    __shared__ bf16_t sX[64 * 128];
    __shared__ bf16_t sW[128 * 128];
    const int tid = threadIdx.x;
    const int row0 = blockIdx.x * 64;
    // stage X tile: 64 rows x 128 bf16 (16B chunks)
#pragma unroll
    for (int it = 0; it < 4; ++it) {
        int idx = tid + it * 256;  // 0..1023
        int r = idx >> 4, c8 = idx & 15;
        int gr = row0 + r;
        uint4 v = make_uint4(0, 0, 0, 0);
        if (gr < N) v = *(const uint4*)(X + (size_t)gr * 128 + c8 * 8);
        *(uint4*)(&sX[r * 128 + c8 * 8]) = v;
    }
    // stage W slice: 128 (out cols) x 128 (k)
#pragma unroll
    for (int it = 0; it < 8; ++it) {
        int idx = tid + it * 256;  // 0..2047
        int r = idx >> 4, c8 = idx & 15;
        uint4 v = *(const uint4*)(Wt + (size_t)(coloff + r) * 128 + c8 * 8);
        *(uint4*)(&sW[r * 128 + c8 * 8]) = v;
    }
    __syncthreads();
    const int wave = tid >> 6, lane = tid & 63;
    const int m = lane & 15, q = lane >> 4;
    const int wrow = wave * 16;
    f32x4 acc[8];
#pragma unroll
    for (int t = 0; t < 8; ++t) acc[t] = (f32x4){0.f, 0.f, 0.f, 0.f};
#pragma unroll
    for (int kk = 0; kk < 4; ++kk) {
        bf16x8 af = *(const bf16x8*)(&sX[(wrow + m) * 128 + kk * 32 + q * 8]);
#pragma unroll
        for (int t = 0; t < 8; ++t) {
            bf16x8 bfr = *(const bf16x8*)(&sW[(t * 16 + m) * 128 + kk * 32 + q * 8]);
            acc[t] = __builtin_amdgcn_mfma_f32_16x16x32_bf16(af, bfr, acc[t], 0, 0, 0);
        }
    }
    // C/D layout: col = lane&15 (+t*16), row = (lane>>4)*4 + j   [verified m89/m91]
#pragma unroll
    for (int t = 0; t < 8; ++t) {
        int col = coloff + t * 16 + m;
        float bv = bias ? bias[col] : 0.f;
        float b2v = bias2 ? bias2[col] : 0.f;
#pragma unroll
        for (int j = 0; j < 4; ++j) {
            int r = row0 + wrow + q * 4 + j;
            if (r < N) {
                float v = acc[t][j] + bv;
                if (rowscale) v += rowscale[r] * b2v;
                if (relu_flag) v = fmaxf(v, 0.f);
                Y[(size_t)r * ldc + col] = (bf16_t)v;
            }
        }
    }
}

// ---------------- edge aggregation: q[n] = sum_{e:dst=n} relu(a[n]+b[src]) + relu(a[n]+b[n]) --
// ab: [N,256] bf16, cols 0..127 = a (b1 folded in), 128..255 = b. One wave per node.
__global__ __launch_bounds__(256) void gather_kernel(const bf16_t* __restrict__ ab,
                                                     const int* __restrict__ row_ptr,
                                                     const int* __restrict__ colarr,
                                                     bf16_t* __restrict__ q, int N) {
    int wid = (blockIdx.x * 256 + threadIdx.x) >> 6;
    int lane = threadIdx.x & 63;
    if (wid >= N) return;
    const u32* abu = (const u32*)ab;  // row = 128 u32 (a: 0..63, b: 64..127)
    u32 a2 = abu[(size_t)wid * 128 + lane];
    float ax = bflo(a2), ay = bfhi(a2);
    u32 bs = abu[(size_t)wid * 128 + 64 + lane];  // self loop
    float qx = fmaxf(ax + bflo(bs), 0.f);
    float qy = fmaxf(ay + bfhi(bs), 0.f);
    int e0 = row_ptr[wid], e1 = row_ptr[wid + 1];
    for (int e = e0; e < e1; ++e) {
        int src = colarr[e];
        u32 b2 = abu[(size_t)src * 128 + 64 + lane];
        qx += fmaxf(ax + bflo(b2), 0.f);
        qy += fmaxf(ay + bfhi(b2), 0.f);
    }
    ((u32*)q)[(size_t)wid * 64 + lane] = bfpack(qx, qy);
}

// ---------------- pooling: batch is sorted -> run-accumulate per wave, flush on change -------
__global__ __launch_bounds__(256) void pool_kernel(const bf16_t* __restrict__ agg,
                                                   const int* __restrict__ batch,
                                                   float* __restrict__ pooled,
                                                   int* __restrict__ cntg, int N) {
    int wid = (blockIdx.x * 256 + threadIdx.x) >> 6;
    int lane = threadIdx.x & 63;
    int n0 = wid * 32;
    if (n0 >= N) return;
    int n1 = min(n0 + 32, N);
    const u32* au = (const u32*)agg;
    int gcur = batch[n0];
    float sx = 0.f, sy = 0.f;
    int cnt = 0;
    for (int n = n0; n < n1; ++n) {
        int g = batch[n];
        if (g != gcur) {
            atomicAdd(&pooled[gcur * 128 + lane * 2], sx);
            atomicAdd(&pooled[gcur * 128 + lane * 2 + 1], sy);
            if (lane == 0) atomicAdd(&cntg[gcur], cnt);
            gcur = g; sx = 0.f; sy = 0.f; cnt = 0;
        }
        u32 v = au[(size_t)n * 64 + lane];
        sx += bflo(v);
        sy += bfhi(v);
        ++cnt;
    }
    atomicAdd(&pooled[gcur * 128 + lane * 2], sx);
    atomicAdd(&pooled[gcur * 128 + lane * 2 + 1], sy);
    if (lane == 0) atomicAdd(&cntg[gcur], cnt);
}

// ---------------- final: out[g,o] = (pooled[g]/max(cnt,1)) @ out_w + out_b ----------------
__global__ __launch_bounds__(256) void final_kernel(const float* __restrict__ pooled,
                                                    const int* __restrict__ cntg,
                                                    const float* __restrict__ out_w,
                                                    const float* __restrict__ out_b,
                                                    float* __restrict__ out, int total) {
    int idx = blockIdx.x * 256 + threadIdx.x;
    if (idx >= total) return;
    int g = idx >> 6, o = idx & 63;
    float c = fmaxf((float)cntg[g], 1.0f);
    float s = 0.f;
#pragma unroll 4
    for (int k = 0; k < 128; ++k) s += pooled[g * 128 + k] * out_w[k * 64 + o];
    out[idx] = s / c + out_b[o];
}

extern "C" void kernel_launch(void* const* d_in, const int* in_sizes, int n_in, void* d_out,
                              int out_size, void* d_ws, size_t ws_size, hipStream_t stream) {
    const float* x = (const float*)d_in[0];
    const int* ei = (const int*)d_in[1];
    const int* batch = (const int*)d_in[3];
    const float* cw[3][6];  // lin_w, lin_b, w1, b1, w2, b2
    for (int l = 0; l < 3; ++l)
        for (int j = 0; j < 6; ++j) cw[l][j] = (const float*)d_in[4 + l * 6 + j];
    const float* out_w = (const float*)d_in[22];
    const float* out_b = (const float*)d_in[23];
    float* out = (float*)d_out;

    const int N = in_sizes[0] / 128;
    const int E = in_sizes[1] / 2;
    const int G = out_size / 64;

    // ---- workspace layout ----
    char* base = (char*)d_ws;
    size_t off = 0;
    auto alloc = [&](size_t b) { size_t o = off; off += (b + 255) & ~(size_t)255; return o; };
    int* deg = (int*)(base + alloc((size_t)N * 4));
    int* cursor = (int*)(base + alloc((size_t)N * 4));
    float* pooled = (float*)(base + alloc((size_t)G * 128 * 4));
    int* cntg = (int*)(base + alloc((size_t)G * 4));
    const size_t zero_bytes = off;
    int* row_ptr = (int*)(base + alloc((size_t)(N + 1) * 4));
    float* cntp1f = (float*)(base + alloc((size_t)N * 4));
    int* colarr = (int*)(base + alloc((size_t)E * 4));
    bf16_t* xb = (bf16_t*)(base + alloc((size_t)N * 128 * 2));
    bf16_t* hq = (bf16_t*)(base + alloc((size_t)N * 128 * 2));   // h, then q (h dead after GEMM2)
    bf16_t* ab = (bf16_t*)(base + alloc((size_t)N * 256 * 2));   // [a|b], then agg (ab dead after gather)
    bf16_t* W1t[3]; bf16_t* W12t[3]; bf16_t* W2t[3]; float* bias256[3];
    for (int l = 0; l < 3; ++l) {
        W1t[l] = (bf16_t*)(base + alloc(16384 * 2));
        W12t[l] = (bf16_t*)(base + alloc(32768 * 2));
        W2t[l] = (bf16_t*)(base + alloc(16384 * 2));
        bias256[l] = (float*)(base + alloc(256 * 4));
    }
    (void)ws_size; (void)n_in;

    hipMemsetAsync(d_ws, 0, zero_bytes, stream);

    // prep
    convx_kernel<<<(N * 128 / 4 + 255) / 256, 256, 0, stream>>>(x, xb, N * 128);
    for (int l = 0; l < 3; ++l)
        prepw_kernel<<<257, 256, 0, stream>>>(cw[l][0], cw[l][2], cw[l][4], cw[l][3], W1t[l],
                                              W12t[l], W2t[l], bias256[l]);
    // CSR
    deg_kernel<<<(E + 255) / 256, 256, 0, stream>>>(ei, deg, E);
    scan_kernel<<<1, 1024, 0, stream>>>(deg, row_ptr, cntp1f, N);
    scatter_kernel<<<(E + 255) / 256, 256, 0, stream>>>(ei, row_ptr, cursor, colarr, E);

    const int gblocks = (N + 63) / 64;
    auto gemm = [&](const bf16_t* X, const bf16_t* Wt, const float* bias, const float* bias2,
                    const float* rowscale, bf16_t* Y, int ncol, int relu_flag) {
        gemm_node<<<dim3(gblocks, ncol / 128), 256, 0, stream>>>(X, Wt, bias, bias2, rowscale, Y,
                                                                 N, ncol, relu_flag);
    };

    const bf16_t* Xin = xb;
    for (int l = 0; l < 3; ++l) {
        // h = Xin @ lin_w + lin_b          (Xin already relu'd by previous layer's epilogue)
        gemm(Xin, W1t[l], cw[l][1], nullptr, nullptr, hq, 128, 0);
        // [a|b] = h @ [w1_top|w1_bot] + [b1|0]
        gemm(hq, W12t[l], bias256[l], nullptr, nullptr, ab, 256, 0);
        // q[n] = sum_in-edges relu(a[n]+b[src]) + relu(a[n]+b[n])
        gather_kernel<<<(N * 64 + 255) / 256, 256, 0, stream>>>(ab, row_ptr, colarr, hq, N);
        // agg = relu(q @ w2 + (deg+1)*b2)  -> stored over ab region (ab dead)
        gemm(hq, W2t[l], nullptr, cw[l][5], cntp1f, ab, 128, 1);
        Xin = ab;
    }

    pool_kernel<<<((N + 31) / 32 * 64 + 255) / 256, 256, 0, stream>>>(Xin, batch, pooled, cntg, N);
    final_kernel<<<(G * 64 + 255) / 256, 256, 0, stream>>>(pooled, cntg, out_w, out_b, out,
                                                           G * 64);
}

// Round 2
// 622.033 us; speedup vs baseline: 1.3758x; 1.3758x over previous
//
#include <hip/hip_runtime.h>
#include <hip/hip_bf16.h>

// MPNN on MI355X.
// Key identity: sum_e relu(a[dst]+b[src]) @ w2 == (sum_e relu(a[dst]+b[src])) @ w2
// -> per-edge work is only gather+add+relu+accumulate; all GEMMs are per-node.
// a = h@w1[:128] + b1, b = h@w1[128:].  b2 enters as (indeg+1)*b2 per node.
// All intermediates bf16 (absmax threshold is bf16-grade 0.26).

typedef __bf16 bf16_t;
typedef bf16_t bf16x8 __attribute__((ext_vector_type(8)));
typedef float f32x4 __attribute__((ext_vector_type(4)));
typedef unsigned int u32;
typedef unsigned short u16;

__device__ __forceinline__ float bflo(u32 v) { return __builtin_bit_cast(float, v << 16); }
__device__ __forceinline__ float bfhi(u32 v) { return __builtin_bit_cast(float, v & 0xffff0000u); }
__device__ __forceinline__ u32 bfpack(float x, float y) {
    u16 a = __builtin_bit_cast(u16, (bf16_t)x);
    u16 b = __builtin_bit_cast(u16, (bf16_t)y);
    return (u32)a | ((u32)b << 16);
}

// ---------------- prep: fp32 x -> bf16 ----------------
__global__ __launch_bounds__(256) void convx_kernel(const float* __restrict__ x,
                                                    bf16_t* __restrict__ xb, int total) {
    int i = (blockIdx.x * 256 + threadIdx.x) * 4;
    if (i >= total) return;
    float4 v = *(const float4*)(x + i);
    u32 o0 = bfpack(v.x, v.y), o1 = bfpack(v.z, v.w);
    *(uint2*)(xb + i) = make_uint2(o0, o1);
}

// ---------------- prep: weights -> transposed bf16 (one launch per layer) ----------------
__global__ __launch_bounds__(256) void prepw_kernel(const float* __restrict__ lin_w,
                                                    const float* __restrict__ w1,
                                                    const float* __restrict__ w2,
                                                    const float* __restrict__ b1,
                                                    bf16_t* __restrict__ W1t,
                                                    bf16_t* __restrict__ W12t,
                                                    bf16_t* __restrict__ W2t,
                                                    float* __restrict__ bias256) {
    int idx = blockIdx.x * 256 + threadIdx.x;
    if (idx < 16384) {
        int j = idx >> 7, k = idx & 127;
        W1t[idx] = (bf16_t)lin_w[k * 128 + j];
    } else if (idx < 16384 + 32768) {
        int i = idx - 16384;
        int j = i >> 7, k = i & 127;
        float v = (j < 128) ? w1[k * 128 + j] : w1[(128 + k) * 128 + (j - 128)];
        W12t[i] = (bf16_t)v;
    } else if (idx < 16384 + 32768 + 16384) {
        int i = idx - 49152;
        int j = i >> 7, k = i & 127;
        W2t[i] = (bf16_t)w2[k * 128 + j];
    } else if (idx < 65792) {
        int i = idx - 65536;
        bias256[i] = (i < 128) ? b1[i] : 0.f;
    }
}

// ---------------- CSR build ----------------
__global__ __launch_bounds__(256) void deg_kernel(const int* __restrict__ ei,
                                                  int* __restrict__ deg, int E) {
    int e = blockIdx.x * 256 + threadIdx.x;
    if (e < E) atomicAdd(&deg[ei[E + e]], 1);  // dst = ei[1][e]
}

// hierarchical exclusive scan: pass1 block-reduce, pass2 scan block sums, pass3 local scan+offset
__global__ __launch_bounds__(256) void scan_pass1(const int* __restrict__ deg,
                                                  int* __restrict__ bsum, int N) {
    __shared__ int red[4];
    int t = threadIdx.x;
    int base = blockIdx.x * 1024 + t * 4;
    int4 v = make_int4(0, 0, 0, 0);
    if (base + 3 < N) v = *(const int4*)(deg + base);
    else {
        if (base + 0 < N) v.x = deg[base + 0];
        if (base + 1 < N) v.y = deg[base + 1];
        if (base + 2 < N) v.z = deg[base + 2];
    }
    int s = v.x + v.y + v.z + v.w;
#pragma unroll
    for (int off = 1; off < 64; off <<= 1) s += __shfl_xor(s, off);
    if ((t & 63) == 0) red[t >> 6] = s;
    __syncthreads();
    if (t == 0) bsum[blockIdx.x] = red[0] + red[1] + red[2] + red[3];
}

__global__ __launch_bounds__(256) void scan_pass2(int* __restrict__ bsum, int nb) {
    __shared__ int sh[256];
    int t = threadIdx.x;
    int v = (t < nb) ? bsum[t] : 0;
    sh[t] = v;
    __syncthreads();
#pragma unroll
    for (int off = 1; off < 256; off <<= 1) {
        int u = (t >= off) ? sh[t - off] : 0;
        __syncthreads();
        sh[t] += u;
        __syncthreads();
    }
    if (t < nb) bsum[t] = sh[t] - v;  // exclusive prefix of block sums, in place
}

__global__ __launch_bounds__(256) void scan_pass3(const int* __restrict__ deg,
                                                  const int* __restrict__ bsum,
                                                  int* __restrict__ row_ptr,
                                                  float* __restrict__ cntp1f, int N) {
    __shared__ int sh[256];
    int t = threadIdx.x;
    int base = blockIdx.x * 1024 + t * 4;
    int4 v = make_int4(0, 0, 0, 0);
    if (base + 3 < N) v = *(const int4*)(deg + base);
    else {
        if (base + 0 < N) v.x = deg[base + 0];
        if (base + 1 < N) v.y = deg[base + 1];
        if (base + 2 < N) v.z = deg[base + 2];
    }
    int s = v.x + v.y + v.z + v.w;
    sh[t] = s;
    __syncthreads();
#pragma unroll
    for (int off = 1; off < 256; off <<= 1) {
        int u = (t >= off) ? sh[t - off] : 0;
        __syncthreads();
        sh[t] += u;
        __syncthreads();
    }
    int pre = sh[t] - s + bsum[blockIdx.x];
    int vv[4] = {v.x, v.y, v.z, v.w};
#pragma unroll
    for (int i = 0; i < 4; ++i) {
        int idx = base + i;
        if (idx < N) {
            row_ptr[idx] = pre;
            cntp1f[idx] = (float)(vv[i] + 1);
            pre += vv[i];
            if (idx == N - 1) row_ptr[N] = pre;
        }
    }
}

__global__ __launch_bounds__(256) void scatter_kernel(const int* __restrict__ ei,
                                                      const int* __restrict__ row_ptr,
                                                      int* __restrict__ cursor,
                                                      int* __restrict__ colarr, int E) {
    int e = blockIdx.x * 256 + threadIdx.x;
    if (e >= E) return;
    int d = ei[E + e], s = ei[e];
    int pos = row_ptr[d] + atomicAdd(&cursor[d], 1);
    colarr[pos] = s;
}

// ---------------- node GEMM: Y[N,ldc slice] = X[N,128] @ W + bias (MFMA bf16) ----------------
__global__ __launch_bounds__(256) void gemm_node(const bf16_t* __restrict__ X,
                                                 const bf16_t* __restrict__ Wt,
                                                 const float* __restrict__ bias,
                                                 const float* __restrict__ bias2,
                                                 const float* __restrict__ rowscale,
                                                 bf16_t* __restrict__ Y, int N, int ldc,
                                                 int relu_flag) {
    const int coloff = blockIdx.y * 128;
    __shared__ bf16_t sX[64 * 128];
    __shared__ bf16_t sW[128 * 128];
    const int tid = threadIdx.x;
    const int row0 = blockIdx.x * 64;
#pragma unroll
    for (int it = 0; it < 4; ++it) {
        int idx = tid + it * 256;
        int r = idx >> 4, c8 = idx & 15;
        int gr = row0 + r;
        uint4 v = make_uint4(0, 0, 0, 0);
        if (gr < N) v = *(const uint4*)(X + (size_t)gr * 128 + c8 * 8);
        *(uint4*)(&sX[r * 128 + c8 * 8]) = v;
    }
#pragma unroll
    for (int it = 0; it < 8; ++it) {
        int idx = tid + it * 256;
        int r = idx >> 4, c8 = idx & 15;
        uint4 v = *(const uint4*)(Wt + (size_t)(coloff + r) * 128 + c8 * 8);
        *(uint4*)(&sW[r * 128 + c8 * 8]) = v;
    }
    __syncthreads();
    const int wave = tid >> 6, lane = tid & 63;
    const int m = lane & 15, q = lane >> 4;
    const int wrow = wave * 16;
    f32x4 acc[8];
#pragma unroll
    for (int t = 0; t < 8; ++t) acc[t] = (f32x4){0.f, 0.f, 0.f, 0.f};
#pragma unroll
    for (int kk = 0; kk < 4; ++kk) {
        bf16x8 af = *(const bf16x8*)(&sX[(wrow + m) * 128 + kk * 32 + q * 8]);
#pragma unroll
        for (int t = 0; t < 8; ++t) {
            bf16x8 bfr = *(const bf16x8*)(&sW[(t * 16 + m) * 128 + kk * 32 + q * 8]);
            acc[t] = __builtin_amdgcn_mfma_f32_16x16x32_bf16(af, bfr, acc[t], 0, 0, 0);
        }
    }
#pragma unroll
    for (int t = 0; t < 8; ++t) {
        int col = coloff + t * 16 + m;
        float bv = bias ? bias[col] : 0.f;
        float b2v = bias2 ? bias2[col] : 0.f;
#pragma unroll
        for (int j = 0; j < 4; ++j) {
            int r = row0 + wrow + q * 4 + j;
            if (r < N) {
                float v = acc[t][j] + bv;
                if (rowscale) v += rowscale[r] * b2v;
                if (relu_flag) v = fmaxf(v, 0.f);
                Y[(size_t)r * ldc + col] = (bf16_t)v;
            }
        }
    }
}

// ---------------- edge aggregation v2: 4 edges in flight per wave ----------------
// ab: [N,256] bf16 = [N,32] uint4; a = uint4 0..15, b = uint4 16..31 of each row.
// Wave per node. lane group g=lane>>4 handles edge e+g; lane-in-group l=lane&15
// loads uint4 (8 bf16 cols l*8..l*8+7). Final butterfly over groups (xor 16,32).
__global__ __launch_bounds__(256) void gather_kernel(const bf16_t* __restrict__ ab,
                                                     const int* __restrict__ row_ptr,
                                                     const int* __restrict__ colarr,
                                                     bf16_t* __restrict__ q, int N) {
    int wid = (blockIdx.x * 256 + threadIdx.x) >> 6;
    int lane = threadIdx.x & 63;
    if (wid >= N) return;
    const uint4* abu4 = (const uint4*)ab;
    const int g = lane >> 4, l = lane & 15;
    uint4 A = abu4[(size_t)wid * 32 + l];
    float a0 = bflo(A.x), a1 = bfhi(A.x), a2 = bflo(A.y), a3 = bfhi(A.y);
    float a4 = bflo(A.z), a5 = bfhi(A.z), a6 = bflo(A.w), a7 = bfhi(A.w);
    float c0 = 0.f, c1 = 0.f, c2 = 0.f, c3 = 0.f, c4 = 0.f, c5 = 0.f, c6 = 0.f, c7 = 0.f;
    if (g == 0) {  // self loop, counted once
        uint4 B = abu4[(size_t)wid * 32 + 16 + l];
        c0 = fmaxf(a0 + bflo(B.x), 0.f); c1 = fmaxf(a1 + bfhi(B.x), 0.f);
        c2 = fmaxf(a2 + bflo(B.y), 0.f); c3 = fmaxf(a3 + bfhi(B.y), 0.f);
        c4 = fmaxf(a4 + bflo(B.z), 0.f); c5 = fmaxf(a5 + bfhi(B.z), 0.f);
        c6 = fmaxf(a6 + bflo(B.w), 0.f); c7 = fmaxf(a7 + bfhi(B.w), 0.f);
    }
    int e0 = row_ptr[wid], e1 = row_ptr[wid + 1];
    for (int e = e0; e < e1; e += 4) {
        int edge = e + g;
        if (edge < e1) {
            int src = colarr[edge];
            uint4 B = abu4[(size_t)src * 32 + 16 + l];
            c0 += fmaxf(a0 + bflo(B.x), 0.f); c1 += fmaxf(a1 + bfhi(B.x), 0.f);
            c2 += fmaxf(a2 + bflo(B.y), 0.f); c3 += fmaxf(a3 + bfhi(B.y), 0.f);
            c4 += fmaxf(a4 + bflo(B.z), 0.f); c5 += fmaxf(a5 + bfhi(B.z), 0.f);
            c6 += fmaxf(a6 + bflo(B.w), 0.f); c7 += fmaxf(a7 + bfhi(B.w), 0.f);
        }
    }
    // sum across the 4 groups
#pragma unroll
    for (int off = 16; off < 64; off <<= 1) {
        c0 += __shfl_xor(c0, off); c1 += __shfl_xor(c1, off);
        c2 += __shfl_xor(c2, off); c3 += __shfl_xor(c3, off);
        c4 += __shfl_xor(c4, off); c5 += __shfl_xor(c5, off);
        c6 += __shfl_xor(c6, off); c7 += __shfl_xor(c7, off);
    }
    if (g == 0) {
        uint4 o;
        o.x = bfpack(c0, c1); o.y = bfpack(c2, c3);
        o.z = bfpack(c4, c5); o.w = bfpack(c6, c7);
        ((uint4*)q)[(size_t)wid * 16 + l] = o;
    }
}

// ---------------- pooling ----------------
__global__ __launch_bounds__(256) void pool_kernel(const bf16_t* __restrict__ agg,
                                                   const int* __restrict__ batch,
                                                   float* __restrict__ pooled,
                                                   int* __restrict__ cntg, int N) {
    int wid = (blockIdx.x * 256 + threadIdx.x) >> 6;
    int lane = threadIdx.x & 63;
    int n0 = wid * 32;
    if (n0 >= N) return;
    int n1 = min(n0 + 32, N);
    const u32* au = (const u32*)agg;
    int gcur = batch[n0];
    float sx = 0.f, sy = 0.f;
    int cnt = 0;
    for (int n = n0; n < n1; ++n) {
        int g = batch[n];
        if (g != gcur) {
            atomicAdd(&pooled[gcur * 128 + lane * 2], sx);
            atomicAdd(&pooled[gcur * 128 + lane * 2 + 1], sy);
            if (lane == 0) atomicAdd(&cntg[gcur], cnt);
            gcur = g; sx = 0.f; sy = 0.f; cnt = 0;
        }
        u32 v = au[(size_t)n * 64 + lane];
        sx += bflo(v);
        sy += bfhi(v);
        ++cnt;
    }
    atomicAdd(&pooled[gcur * 128 + lane * 2], sx);
    atomicAdd(&pooled[gcur * 128 + lane * 2 + 1], sy);
    if (lane == 0) atomicAdd(&cntg[gcur], cnt);
}

// ---------------- final ----------------
__global__ __launch_bounds__(256) void final_kernel(const float* __restrict__ pooled,
                                                    const int* __restrict__ cntg,
                                                    const float* __restrict__ out_w,
                                                    const float* __restrict__ out_b,
                                                    float* __restrict__ out, int total) {
    int idx = blockIdx.x * 256 + threadIdx.x;
    if (idx >= total) return;
    int g = idx >> 6, o = idx & 63;
    float c = fmaxf((float)cntg[g], 1.0f);
    float s = 0.f;
#pragma unroll 4
    for (int k = 0; k < 128; ++k) s += pooled[g * 128 + k] * out_w[k * 64 + o];
    out[idx] = s / c + out_b[o];
}

extern "C" void kernel_launch(void* const* d_in, const int* in_sizes, int n_in, void* d_out,
                              int out_size, void* d_ws, size_t ws_size, hipStream_t stream) {
    const float* x = (const float*)d_in[0];
    const int* ei = (const int*)d_in[1];
    const int* batch = (const int*)d_in[3];
    const float* cw[3][6];  // lin_w, lin_b, w1, b1, w2, b2
    for (int l = 0; l < 3; ++l)
        for (int j = 0; j < 6; ++j) cw[l][j] = (const float*)d_in[4 + l * 6 + j];
    const float* out_w = (const float*)d_in[22];
    const float* out_b = (const float*)d_in[23];
    float* out = (float*)d_out;

    const int N = in_sizes[0] / 128;
    const int E = in_sizes[1] / 2;
    const int G = out_size / 64;

    // ---- workspace layout ----
    char* base = (char*)d_ws;
    size_t off = 0;
    auto alloc = [&](size_t b) { size_t o = off; off += (b + 255) & ~(size_t)255; return o; };
    int* deg = (int*)(base + alloc((size_t)N * 4));
    int* cursor = (int*)(base + alloc((size_t)N * 4));
    float* pooled = (float*)(base + alloc((size_t)G * 128 * 4));
    int* cntg = (int*)(base + alloc((size_t)G * 4));
    const size_t zero_bytes = off;
    int* row_ptr = (int*)(base + alloc((size_t)(N + 1) * 4));
    float* cntp1f = (float*)(base + alloc((size_t)N * 4));
    int* colarr = (int*)(base + alloc((size_t)E * 4));
    int* bsum = (int*)(base + alloc(256 * 4));
    bf16_t* xb = (bf16_t*)(base + alloc((size_t)N * 128 * 2));
    bf16_t* hq = (bf16_t*)(base + alloc((size_t)N * 128 * 2));   // h, then q
    bf16_t* ab = (bf16_t*)(base + alloc((size_t)N * 256 * 2));   // [a|b], then agg
    bf16_t* W1t[3]; bf16_t* W12t[3]; bf16_t* W2t[3]; float* bias256[3];
    for (int l = 0; l < 3; ++l) {
        W1t[l] = (bf16_t*)(base + alloc(16384 * 2));
        W12t[l] = (bf16_t*)(base + alloc(32768 * 2));
        W2t[l] = (bf16_t*)(base + alloc(16384 * 2));
        bias256[l] = (float*)(base + alloc(256 * 4));
    }
    (void)ws_size; (void)n_in;

    hipMemsetAsync(d_ws, 0, zero_bytes, stream);

    // prep
    convx_kernel<<<(N * 128 / 4 + 255) / 256, 256, 0, stream>>>(x, xb, N * 128);
    for (int l = 0; l < 3; ++l)
        prepw_kernel<<<257, 256, 0, stream>>>(cw[l][0], cw[l][2], cw[l][4], cw[l][3], W1t[l],
                                              W12t[l], W2t[l], bias256[l]);
    // CSR
    const int nb = (N + 1023) / 1024;
    deg_kernel<<<(E + 255) / 256, 256, 0, stream>>>(ei, deg, E);
    scan_pass1<<<nb, 256, 0, stream>>>(deg, bsum, N);
    scan_pass2<<<1, 256, 0, stream>>>(bsum, nb);
    scan_pass3<<<nb, 256, 0, stream>>>(deg, bsum, row_ptr, cntp1f, N);
    scatter_kernel<<<(E + 255) / 256, 256, 0, stream>>>(ei, row_ptr, cursor, colarr, E);

    const int gblocks = (N + 63) / 64;
    auto gemm = [&](const bf16_t* X, const bf16_t* Wt, const float* bias, const float* bias2,
                    const float* rowscale, bf16_t* Y, int ncol, int relu_flag) {
        gemm_node<<<dim3(gblocks, ncol / 128), 256, 0, stream>>>(X, Wt, bias, bias2, rowscale, Y,
                                                                 N, ncol, relu_flag);
    };

    const bf16_t* Xin = xb;
    for (int l = 0; l < 3; ++l) {
        gemm(Xin, W1t[l], cw[l][1], nullptr, nullptr, hq, 128, 0);
        gemm(hq, W12t[l], bias256[l], nullptr, nullptr, ab, 256, 0);
        gather_kernel<<<(N * 64 + 255) / 256, 256, 0, stream>>>(ab, row_ptr, colarr, hq, N);
        gemm(hq, W2t[l], nullptr, cw[l][5], cntp1f, ab, 128, 1);
        Xin = ab;
    }

    pool_kernel<<<((N + 31) / 32 * 64 + 255) / 256, 256, 0, stream>>>(Xin, batch, pooled, cntg, N);
    final_kernel<<<(G * 64 + 255) / 256, 256, 0, stream>>>(pooled, cntg, out_w, out_b, out,
                                                           G * 64);
}

// Round 3
// 566.705 us; speedup vs baseline: 1.5101x; 1.0976x over previous
//
#include <hip/hip_runtime.h>
#include <hip/hip_bf16.h>

// MPNN on MI355X.
// Identities used:
//  (1) sum_e relu(a[dst]+b[src]) @ w2 == (sum_e relu(a[dst]+b[src])) @ w2
//  (2) (x@lin_w+lin_b)@w1 == x@(lin_w@w1) + (lin_b@w1)  -> lin GEMM composed into w1 GEMM
// Per layer: ONE 256-col GEMM (composed), gather(edge add+relu+acc), ONE 128-col GEMM (w2).
// b2 enters exactly as (indeg+1)*b2 per node via rowscale epilogue.

typedef __bf16 bf16_t;
typedef bf16_t bf16x8 __attribute__((ext_vector_type(8)));
typedef float f32x4 __attribute__((ext_vector_type(4)));
typedef unsigned int u32;
typedef unsigned short u16;

__device__ __forceinline__ float bflo(u32 v) { return __builtin_bit_cast(float, v << 16); }
__device__ __forceinline__ float bfhi(u32 v) { return __builtin_bit_cast(float, v & 0xffff0000u); }
__device__ __forceinline__ u32 bfpack(float x, float y) {
    u16 a = __builtin_bit_cast(u16, (bf16_t)x);
    u16 b = __builtin_bit_cast(u16, (bf16_t)y);
    return (u32)a | ((u32)b << 16);
}

// ---------------- prep: fp32 x -> bf16 ----------------
__global__ __launch_bounds__(256) void convx_kernel(const float* __restrict__ x,
                                                    bf16_t* __restrict__ xb, int total) {
    int i = (blockIdx.x * 256 + threadIdx.x) * 4;
    if (i >= total) return;
    float4 v = *(const float4*)(x + i);
    u32 o0 = bfpack(v.x, v.y), o1 = bfpack(v.z, v.w);
    *(uint2*)(xb + i) = make_uint2(o0, o1);
}

// ---------------- prep: compose lin into w1, transpose to bf16 ----------------
// W12ct[j][k] = sum_c lin_w[k][c] * w1sel(c,j),  j in [0,256), k in [0,128)
//   w1sel(c,j) = j<128 ? w1[c][j] : w1[128+c][j-128]
// bias256c[j] = sum_c lin_b[c] * w1sel(c,j) + (j<128 ? b1[j] : 0)
// W2t[j][k] = w2[k][j]
__global__ __launch_bounds__(256) void prepw_kernel(const float* __restrict__ lin_w,
                                                    const float* __restrict__ lin_b,
                                                    const float* __restrict__ w1,
                                                    const float* __restrict__ b1,
                                                    const float* __restrict__ w2,
                                                    bf16_t* __restrict__ W12ct,
                                                    bf16_t* __restrict__ W2t,
                                                    float* __restrict__ bias256c) {
    int idx = blockIdx.x * 256 + threadIdx.x;
    if (idx < 32768) {
        int j = idx >> 7, k = idx & 127;
        const float* wcol = (j < 128) ? (w1 + j) : (w1 + 128 * 128 + (j - 128));
        const float* lrow = lin_w + k * 128;
        float s = 0.f;
#pragma unroll 4
        for (int c = 0; c < 128; ++c) s += lrow[c] * wcol[c * 128];
        W12ct[idx] = (bf16_t)s;
    } else if (idx < 32768 + 16384) {
        int i = idx - 32768;
        int j = i >> 7, k = i & 127;
        W2t[i] = (bf16_t)w2[k * 128 + j];
    } else if (idx < 32768 + 16384 + 256) {
        int j = idx - 49152;
        const float* wcol = (j < 128) ? (w1 + j) : (w1 + 128 * 128 + (j - 128));
        float s = (j < 128) ? b1[j] : 0.f;
        for (int c = 0; c < 128; ++c) s += lin_b[c] * wcol[c * 128];
        bias256c[j] = s;
    }
}

// ---------------- CSR build ----------------
__global__ __launch_bounds__(256) void deg_kernel(const int* __restrict__ ei,
                                                  int* __restrict__ deg, int E) {
    int e = blockIdx.x * 256 + threadIdx.x;
    if (e < E) atomicAdd(&deg[ei[E + e]], 1);  // dst = ei[1][e]
}

__global__ __launch_bounds__(256) void scan_pass1(const int* __restrict__ deg,
                                                  int* __restrict__ bsum, int N) {
    __shared__ int red[4];
    int t = threadIdx.x;
    int base = blockIdx.x * 1024 + t * 4;
    int4 v = make_int4(0, 0, 0, 0);
    if (base + 3 < N) v = *(const int4*)(deg + base);
    else {
        if (base + 0 < N) v.x = deg[base + 0];
        if (base + 1 < N) v.y = deg[base + 1];
        if (base + 2 < N) v.z = deg[base + 2];
    }
    int s = v.x + v.y + v.z + v.w;
#pragma unroll
    for (int off = 1; off < 64; off <<= 1) s += __shfl_xor(s, off);
    if ((t & 63) == 0) red[t >> 6] = s;
    __syncthreads();
    if (t == 0) bsum[blockIdx.x] = red[0] + red[1] + red[2] + red[3];
}

__global__ __launch_bounds__(256) void scan_pass2(int* __restrict__ bsum, int nb) {
    __shared__ int sh[256];
    int t = threadIdx.x;
    int v = (t < nb) ? bsum[t] : 0;
    sh[t] = v;
    __syncthreads();
#pragma unroll
    for (int off = 1; off < 256; off <<= 1) {
        int u = (t >= off) ? sh[t - off] : 0;
        __syncthreads();
        sh[t] += u;
        __syncthreads();
    }
    if (t < nb) bsum[t] = sh[t] - v;
}

__global__ __launch_bounds__(256) void scan_pass3(const int* __restrict__ deg,
                                                  const int* __restrict__ bsum,
                                                  int* __restrict__ row_ptr,
                                                  float* __restrict__ cntp1f, int N) {
    __shared__ int sh[256];
    int t = threadIdx.x;
    int base = blockIdx.x * 1024 + t * 4;
    int4 v = make_int4(0, 0, 0, 0);
    if (base + 3 < N) v = *(const int4*)(deg + base);
    else {
        if (base + 0 < N) v.x = deg[base + 0];
        if (base + 1 < N) v.y = deg[base + 1];
        if (base + 2 < N) v.z = deg[base + 2];
    }
    int s = v.x + v.y + v.z + v.w;
    sh[t] = s;
    __syncthreads();
#pragma unroll
    for (int off = 1; off < 256; off <<= 1) {
        int u = (t >= off) ? sh[t - off] : 0;
        __syncthreads();
        sh[t] += u;
        __syncthreads();
    }
    int pre = sh[t] - s + bsum[blockIdx.x];
    int vv[4] = {v.x, v.y, v.z, v.w};
#pragma unroll
    for (int i = 0; i < 4; ++i) {
        int idx = base + i;
        if (idx < N) {
            row_ptr[idx] = pre;
            cntp1f[idx] = (float)(vv[i] + 1);
            pre += vv[i];
            if (idx == N - 1) row_ptr[N] = pre;
        }
    }
}

// XCD-local scatter: block b -> dst-range (b&7) [heuristic: blockIdx%8 == XCD round-robin],
// edge-slice (b>>3). colarr writes for one range stay in one XCD's L2 -> writebacks merge.
__global__ __launch_bounds__(256) void scatter_kernel(const int* __restrict__ ei,
                                                      const int* __restrict__ row_ptr,
                                                      int* __restrict__ cursor,
                                                      int* __restrict__ colarr, int E, int N,
                                                      int S) {
    const int r = blockIdx.x & 7;
    const int sl = blockIdx.x >> 3;
    const int n8 = (N + 7) >> 3;
    const int lo = r * n8, hi = min(N, lo + n8);
    for (int e = sl * 256 + (int)threadIdx.x; e < E; e += S * 256) {
        int d = ei[E + e];
        if (d >= lo && d < hi) {
            int pos = row_ptr[d] + atomicAdd(&cursor[d], 1);
            colarr[pos] = ei[e];
        }
    }
}

// ---------------- node GEMM: Y[N, ldc] = X[N,128] @ Wt^T + epilogue (MFMA bf16) -------------
// 128-row tiles; B-fragment feeds 2 MFMAs; LDS 16B-groups XOR-swizzled (g ^ (row&7)) so the
// 16-lane fragment reads are 2-way bank-aliased (free) instead of 16-way.
__global__ __launch_bounds__(256) void gemm_node(const bf16_t* __restrict__ X,
                                                 const bf16_t* __restrict__ Wt,
                                                 const float* __restrict__ bias,
                                                 const float* __restrict__ bias2,
                                                 const float* __restrict__ rowscale,
                                                 bf16_t* __restrict__ Y, int N, int ldc,
                                                 int relu_flag) {
    const int coloff = blockIdx.y * 128;
    __shared__ bf16_t sX[128 * 128];
    __shared__ bf16_t sW[128 * 128];
    const int tid = threadIdx.x;
    const int row0 = blockIdx.x * 128;
#pragma unroll
    for (int it = 0; it < 8; ++it) {
        int idx = tid + it * 256;
        int r = idx >> 4, c8 = idx & 15;
        int gr = row0 + r;
        uint4 v = make_uint4(0, 0, 0, 0);
        if (gr < N) v = *(const uint4*)(X + (size_t)gr * 128 + c8 * 8);
        *(uint4*)(&sX[r * 128 + (c8 ^ (r & 7)) * 8]) = v;
    }
#pragma unroll
    for (int it = 0; it < 8; ++it) {
        int idx = tid + it * 256;
        int r = idx >> 4, c8 = idx & 15;
        uint4 v = *(const uint4*)(Wt + (size_t)(coloff + r) * 128 + c8 * 8);
        *(uint4*)(&sW[r * 128 + (c8 ^ (r & 7)) * 8]) = v;
    }
    __syncthreads();
    const int wave = tid >> 6, lane = tid & 63;
    const int m = lane & 15, q = lane >> 4;
    const int sw = m & 7;  // row&7 for all rows we read (offsets are multiples of 16)
    f32x4 acc[2][8];
#pragma unroll
    for (int rt = 0; rt < 2; ++rt)
#pragma unroll
        for (int t = 0; t < 8; ++t) acc[rt][t] = (f32x4){0.f, 0.f, 0.f, 0.f};
#pragma unroll
    for (int kk = 0; kk < 4; ++kk) {
        const int g = (kk * 4 + q) ^ sw;
        bf16x8 a0 = *(const bf16x8*)(&sX[(wave * 32 + m) * 128 + g * 8]);
        bf16x8 a1 = *(const bf16x8*)(&sX[(wave * 32 + 16 + m) * 128 + g * 8]);
#pragma unroll
        for (int t = 0; t < 8; ++t) {
            bf16x8 bfr = *(const bf16x8*)(&sW[(t * 16 + m) * 128 + g * 8]);
            acc[0][t] = __builtin_amdgcn_mfma_f32_16x16x32_bf16(a0, bfr, acc[0][t], 0, 0, 0);
            acc[1][t] = __builtin_amdgcn_mfma_f32_16x16x32_bf16(a1, bfr, acc[1][t], 0, 0, 0);
        }
    }
#pragma unroll
    for (int t = 0; t < 8; ++t) {
        int col = coloff + t * 16 + m;
        float bv = bias ? bias[col] : 0.f;
        float b2v = bias2 ? bias2[col] : 0.f;
#pragma unroll
        for (int rt = 0; rt < 2; ++rt) {
#pragma unroll
            for (int j = 0; j < 4; ++j) {
                int r = row0 + wave * 32 + rt * 16 + q * 4 + j;
                if (r < N) {
                    float v = acc[rt][t][j] + bv;
                    if (rowscale) v += rowscale[r] * b2v;
                    if (relu_flag) v = fmaxf(v, 0.f);
                    Y[(size_t)r * ldc + col] = (bf16_t)v;
                }
            }
        }
    }
}

// ---------------- edge aggregation: 4 edges in flight per wave ----------------
__global__ __launch_bounds__(256) void gather_kernel(const bf16_t* __restrict__ ab,
                                                     const int* __restrict__ row_ptr,
                                                     const int* __restrict__ colarr,
                                                     bf16_t* __restrict__ q, int N) {
    int wid = (blockIdx.x * 256 + threadIdx.x) >> 6;
    int lane = threadIdx.x & 63;
    if (wid >= N) return;
    const uint4* abu4 = (const uint4*)ab;
    const int g = lane >> 4, l = lane & 15;
    uint4 A = abu4[(size_t)wid * 32 + l];
    float a0 = bflo(A.x), a1 = bfhi(A.x), a2 = bflo(A.y), a3 = bfhi(A.y);
    float a4 = bflo(A.z), a5 = bfhi(A.z), a6 = bflo(A.w), a7 = bfhi(A.w);
    float c0 = 0.f, c1 = 0.f, c2 = 0.f, c3 = 0.f, c4 = 0.f, c5 = 0.f, c6 = 0.f, c7 = 0.f;
    if (g == 0) {  // self loop
        uint4 B = abu4[(size_t)wid * 32 + 16 + l];
        c0 = fmaxf(a0 + bflo(B.x), 0.f); c1 = fmaxf(a1 + bfhi(B.x), 0.f);
        c2 = fmaxf(a2 + bflo(B.y), 0.f); c3 = fmaxf(a3 + bfhi(B.y), 0.f);
        c4 = fmaxf(a4 + bflo(B.z), 0.f); c5 = fmaxf(a5 + bfhi(B.z), 0.f);
        c6 = fmaxf(a6 + bflo(B.w), 0.f); c7 = fmaxf(a7 + bfhi(B.w), 0.f);
    }
    int e0 = row_ptr[wid], e1 = row_ptr[wid + 1];
    for (int e = e0; e < e1; e += 4) {
        int edge = e + g;
        if (edge < e1) {
            int src = colarr[edge];
            uint4 B = abu4[(size_t)src * 32 + 16 + l];
            c0 += fmaxf(a0 + bflo(B.x), 0.f); c1 += fmaxf(a1 + bfhi(B.x), 0.f);
            c2 += fmaxf(a2 + bflo(B.y), 0.f); c3 += fmaxf(a3 + bfhi(B.y), 0.f);
            c4 += fmaxf(a4 + bflo(B.z), 0.f); c5 += fmaxf(a5 + bfhi(B.z), 0.f);
            c6 += fmaxf(a6 + bflo(B.w), 0.f); c7 += fmaxf(a7 + bfhi(B.w), 0.f);
        }
    }
#pragma unroll
    for (int off = 16; off < 64; off <<= 1) {
        c0 += __shfl_xor(c0, off); c1 += __shfl_xor(c1, off);
        c2 += __shfl_xor(c2, off); c3 += __shfl_xor(c3, off);
        c4 += __shfl_xor(c4, off); c5 += __shfl_xor(c5, off);
        c6 += __shfl_xor(c6, off); c7 += __shfl_xor(c7, off);
    }
    if (g == 0) {
        uint4 o;
        o.x = bfpack(c0, c1); o.y = bfpack(c2, c3);
        o.z = bfpack(c4, c5); o.w = bfpack(c6, c7);
        ((uint4*)q)[(size_t)wid * 16 + l] = o;
    }
}

// ---------------- pooling ----------------
__global__ __launch_bounds__(256) void pool_kernel(const bf16_t* __restrict__ agg,
                                                   const int* __restrict__ batch,
                                                   float* __restrict__ pooled,
                                                   int* __restrict__ cntg, int N) {
    int wid = (blockIdx.x * 256 + threadIdx.x) >> 6;
    int lane = threadIdx.x & 63;
    int n0 = wid * 32;
    if (n0 >= N) return;
    int n1 = min(n0 + 32, N);
    const u32* au = (const u32*)agg;
    int gcur = batch[n0];
    float sx = 0.f, sy = 0.f;
    int cnt = 0;
    for (int n = n0; n < n1; ++n) {
        int g = batch[n];
        if (g != gcur) {
            atomicAdd(&pooled[gcur * 128 + lane * 2], sx);
            atomicAdd(&pooled[gcur * 128 + lane * 2 + 1], sy);
            if (lane == 0) atomicAdd(&cntg[gcur], cnt);
            gcur = g; sx = 0.f; sy = 0.f; cnt = 0;
        }
        u32 v = au[(size_t)n * 64 + lane];
        sx += bflo(v);
        sy += bfhi(v);
        ++cnt;
    }
    atomicAdd(&pooled[gcur * 128 + lane * 2], sx);
    atomicAdd(&pooled[gcur * 128 + lane * 2 + 1], sy);
    if (lane == 0) atomicAdd(&cntg[gcur], cnt);
}

// ---------------- final ----------------
__global__ __launch_bounds__(256) void final_kernel(const float* __restrict__ pooled,
                                                    const int* __restrict__ cntg,
                                                    const float* __restrict__ out_w,
                                                    const float* __restrict__ out_b,
                                                    float* __restrict__ out, int total) {
    int idx = blockIdx.x * 256 + threadIdx.x;
    if (idx >= total) return;
    int g = idx >> 6, o = idx & 63;
    float c = fmaxf((float)cntg[g], 1.0f);
    float s = 0.f;
#pragma unroll 4
    for (int k = 0; k < 128; ++k) s += pooled[g * 128 + k] * out_w[k * 64 + o];
    out[idx] = s / c + out_b[o];
}

extern "C" void kernel_launch(void* const* d_in, const int* in_sizes, int n_in, void* d_out,
                              int out_size, void* d_ws, size_t ws_size, hipStream_t stream) {
    const float* x = (const float*)d_in[0];
    const int* ei = (const int*)d_in[1];
    const int* batch = (const int*)d_in[3];
    const float* cw[3][6];  // lin_w, lin_b, w1, b1, w2, b2
    for (int l = 0; l < 3; ++l)
        for (int j = 0; j < 6; ++j) cw[l][j] = (const float*)d_in[4 + l * 6 + j];
    const float* out_w = (const float*)d_in[22];
    const float* out_b = (const float*)d_in[23];
    float* out = (float*)d_out;

    const int N = in_sizes[0] / 128;
    const int E = in_sizes[1] / 2;
    const int G = out_size / 64;

    // ---- workspace layout ----
    char* base = (char*)d_ws;
    size_t off = 0;
    auto alloc = [&](size_t b) { size_t o = off; off += (b + 255) & ~(size_t)255; return o; };
    int* deg = (int*)(base + alloc((size_t)N * 4));
    int* cursor = (int*)(base + alloc((size_t)N * 4));
    float* pooled = (float*)(base + alloc((size_t)G * 128 * 4));
    int* cntg = (int*)(base + alloc((size_t)G * 4));
    const size_t zero_bytes = off;
    int* row_ptr = (int*)(base + alloc((size_t)(N + 1) * 4));
    float* cntp1f = (float*)(base + alloc((size_t)N * 4));
    int* colarr = (int*)(base + alloc((size_t)E * 4));
    int* bsum = (int*)(base + alloc(256 * 4));
    bf16_t* xb = (bf16_t*)(base + alloc((size_t)N * 128 * 2));  // layer input / agg output
    bf16_t* q = (bf16_t*)(base + alloc((size_t)N * 128 * 2));   // gather output
    bf16_t* ab = (bf16_t*)(base + alloc((size_t)N * 256 * 2));  // [a|b]
    bf16_t* W12ct[3]; bf16_t* W2t[3]; float* bias256c[3];
    for (int l = 0; l < 3; ++l) {
        W12ct[l] = (bf16_t*)(base + alloc(32768 * 2));
        W2t[l] = (bf16_t*)(base + alloc(16384 * 2));
        bias256c[l] = (float*)(base + alloc(256 * 4));
    }
    (void)ws_size; (void)n_in;

    hipMemsetAsync(d_ws, 0, zero_bytes, stream);

    // prep
    convx_kernel<<<(N * 128 / 4 + 255) / 256, 256, 0, stream>>>(x, xb, N * 128);
    for (int l = 0; l < 3; ++l)
        prepw_kernel<<<194, 256, 0, stream>>>(cw[l][0], cw[l][1], cw[l][2], cw[l][3], cw[l][4],
                                              W12ct[l], W2t[l], bias256c[l]);
    // CSR
    const int nb = (N + 1023) / 1024;
    deg_kernel<<<(E + 255) / 256, 256, 0, stream>>>(ei, deg, E);
    scan_pass1<<<nb, 256, 0, stream>>>(deg, bsum, N);
    scan_pass2<<<1, 256, 0, stream>>>(bsum, nb);
    scan_pass3<<<nb, 256, 0, stream>>>(deg, bsum, row_ptr, cntp1f, N);
    const int S = 96;  // slices per dst-range; grid = 8*S
    scatter_kernel<<<8 * S, 256, 0, stream>>>(ei, row_ptr, cursor, colarr, E, N, S);

    const int gblocks = (N + 127) / 128;
    auto gemm = [&](const bf16_t* X, const bf16_t* Wt, const float* bias, const float* bias2,
                    const float* rowscale, bf16_t* Y, int ncol, int relu_flag) {
        gemm_node<<<dim3(gblocks, ncol / 128), 256, 0, stream>>>(X, Wt, bias, bias2, rowscale, Y,
                                                                 N, ncol, relu_flag);
    };

    const bf16_t* Xin = xb;
    for (int l = 0; l < 3; ++l) {
        // ab = Xin @ [Wa|Wb] + [ba|bb]   (lin layer composed in)
        gemm(Xin, W12ct[l], bias256c[l], nullptr, nullptr, ab, 256, 0);
        // q[n] = sum_in-edges relu(a[n]+b[src]) + relu(a[n]+b[n])
        gather_kernel<<<(N * 64 + 255) / 256, 256, 0, stream>>>(ab, row_ptr, colarr, q, N);
        // xb = relu(q @ w2 + (deg+1)*b2)
        gemm(q, W2t[l], nullptr, cw[l][5], cntp1f, xb, 128, 1);
        Xin = xb;
    }

    pool_kernel<<<((N + 31) / 32 * 64 + 255) / 256, 256, 0, stream>>>(Xin, batch, pooled, cntg, N);
    final_kernel<<<(G * 64 + 255) / 256, 256, 0, stream>>>(pooled, cntg, out_w, out_b, out,
                                                           G * 64);
}

// Round 4
// 559.394 us; speedup vs baseline: 1.5298x; 1.0131x over previous
//
#include <hip/hip_runtime.h>
#include <hip/hip_bf16.h>

// MPNN on MI355X.
// Identities used:
//  (1) sum_e relu(a[dst]+b[src]) @ w2 == (sum_e relu(a[dst]+b[src])) @ w2
//  (2) (x@lin_w+lin_b)@w1 == x@(lin_w@w1) + (lin_b@w1)  -> lin GEMM composed into w1 GEMM
// Per layer: ONE 256-col GEMM (composed), gather(edge add+relu+acc), ONE 128-col GEMM (w2).
// Intermediates are FP16 (not bf16): CDNA4 has packed v_pk_add_f16/v_pk_max_f16 -> gather
// VALU work ~2x lower, and fp16's 10-bit mantissa beats bf16's 7 for accuracy.

typedef _Float16 f16_t;
typedef f16_t f16x2 __attribute__((ext_vector_type(2)));
typedef f16_t f16x8 __attribute__((ext_vector_type(8)));
typedef float f32x4 __attribute__((ext_vector_type(4)));
typedef unsigned int u32;
typedef unsigned short u16;

__device__ __forceinline__ float f16lo(u32 v) {
    return (float)__builtin_bit_cast(f16_t, (u16)(v & 0xffff));
}
__device__ __forceinline__ float f16hi(u32 v) {
    return (float)__builtin_bit_cast(f16_t, (u16)(v >> 16));
}
__device__ __forceinline__ u32 f16pack(float x, float y) {
    u16 a = __builtin_bit_cast(u16, (f16_t)x);
    u16 b = __builtin_bit_cast(u16, (f16_t)y);
    return (u32)a | ((u32)b << 16);
}
__device__ __forceinline__ f16x2 relu_add2(f16x2 a, f16x2 b) {
    f16x2 s = a + b;                              // v_pk_add_f16
    return __builtin_elementwise_max(s, (f16x2)0);  // v_pk_max_f16
}

// ---------------- prep: fp32 x -> fp16 ----------------
__global__ __launch_bounds__(256) void convx_kernel(const float* __restrict__ x,
                                                    f16_t* __restrict__ xb, int total) {
    int i = (blockIdx.x * 256 + threadIdx.x) * 4;
    if (i >= total) return;
    float4 v = *(const float4*)(x + i);
    u32 o0 = f16pack(v.x, v.y), o1 = f16pack(v.z, v.w);
    *(uint2*)(xb + i) = make_uint2(o0, o1);
}

// ---------------- prep: compose lin into w1, transpose to fp16 ----------------
__global__ __launch_bounds__(256) void prepw_kernel(const float* __restrict__ lin_w,
                                                    const float* __restrict__ lin_b,
                                                    const float* __restrict__ w1,
                                                    const float* __restrict__ b1,
                                                    const float* __restrict__ w2,
                                                    f16_t* __restrict__ W12ct,
                                                    f16_t* __restrict__ W2t,
                                                    float* __restrict__ bias256c) {
    int idx = blockIdx.x * 256 + threadIdx.x;
    if (idx < 32768) {
        int j = idx >> 7, k = idx & 127;
        const float* wcol = (j < 128) ? (w1 + j) : (w1 + 128 * 128 + (j - 128));
        const float* lrow = lin_w + k * 128;
        float s = 0.f;
#pragma unroll 4
        for (int c = 0; c < 128; ++c) s += lrow[c] * wcol[c * 128];
        W12ct[idx] = (f16_t)s;
    } else if (idx < 32768 + 16384) {
        int i = idx - 32768;
        int j = i >> 7, k = i & 127;
        W2t[i] = (f16_t)w2[k * 128 + j];
    } else if (idx < 32768 + 16384 + 256) {
        int j = idx - 49152;
        const float* wcol = (j < 128) ? (w1 + j) : (w1 + 128 * 128 + (j - 128));
        float s = (j < 128) ? b1[j] : 0.f;
        for (int c = 0; c < 128; ++c) s += lin_b[c] * wcol[c * 128];
        bias256c[j] = s;
    }
}

// ---------------- CSR build ----------------
__global__ __launch_bounds__(256) void deg_kernel(const int* __restrict__ ei,
                                                  int* __restrict__ deg, int E) {
    int e = blockIdx.x * 256 + threadIdx.x;
    if (e < E) atomicAdd(&deg[ei[E + e]], 1);  // dst = ei[1][e]
}

__global__ __launch_bounds__(256) void scan_pass1(const int* __restrict__ deg,
                                                  int* __restrict__ bsum, int N) {
    __shared__ int red[4];
    int t = threadIdx.x;
    int base = blockIdx.x * 1024 + t * 4;
    int4 v = make_int4(0, 0, 0, 0);
    if (base + 3 < N) v = *(const int4*)(deg + base);
    else {
        if (base + 0 < N) v.x = deg[base + 0];
        if (base + 1 < N) v.y = deg[base + 1];
        if (base + 2 < N) v.z = deg[base + 2];
    }
    int s = v.x + v.y + v.z + v.w;
#pragma unroll
    for (int off = 1; off < 64; off <<= 1) s += __shfl_xor(s, off);
    if ((t & 63) == 0) red[t >> 6] = s;
    __syncthreads();
    if (t == 0) bsum[blockIdx.x] = red[0] + red[1] + red[2] + red[3];
}

__global__ __launch_bounds__(256) void scan_pass2(int* __restrict__ bsum, int nb) {
    __shared__ int sh[256];
    int t = threadIdx.x;
    int v = (t < nb) ? bsum[t] : 0;
    sh[t] = v;
    __syncthreads();
#pragma unroll
    for (int off = 1; off < 256; off <<= 1) {
        int u = (t >= off) ? sh[t - off] : 0;
        __syncthreads();
        sh[t] += u;
        __syncthreads();
    }
    if (t < nb) bsum[t] = sh[t] - v;
}

__global__ __launch_bounds__(256) void scan_pass3(const int* __restrict__ deg,
                                                  const int* __restrict__ bsum,
                                                  int* __restrict__ row_ptr,
                                                  float* __restrict__ cntp1f, int N) {
    __shared__ int sh[256];
    int t = threadIdx.x;
    int base = blockIdx.x * 1024 + t * 4;
    int4 v = make_int4(0, 0, 0, 0);
    if (base + 3 < N) v = *(const int4*)(deg + base);
    else {
        if (base + 0 < N) v.x = deg[base + 0];
        if (base + 1 < N) v.y = deg[base + 1];
        if (base + 2 < N) v.z = deg[base + 2];
    }
    int s = v.x + v.y + v.z + v.w;
    sh[t] = s;
    __syncthreads();
#pragma unroll
    for (int off = 1; off < 256; off <<= 1) {
        int u = (t >= off) ? sh[t - off] : 0;
        __syncthreads();
        sh[t] += u;
        __syncthreads();
    }
    int pre = sh[t] - s + bsum[blockIdx.x];
    int vv[4] = {v.x, v.y, v.z, v.w};
#pragma unroll
    for (int i = 0; i < 4; ++i) {
        int idx = base + i;
        if (idx < N) {
            row_ptr[idx] = pre;
            cntp1f[idx] = (float)(vv[i] + 1);
            pre += vv[i];
            if (idx == N - 1) row_ptr[N] = pre;
        }
    }
}

// XCD-local scatter: block b -> dst-range (b&7), edge-slice (b>>3).
__global__ __launch_bounds__(256) void scatter_kernel(const int* __restrict__ ei,
                                                      const int* __restrict__ row_ptr,
                                                      int* __restrict__ cursor,
                                                      int* __restrict__ colarr, int E, int N,
                                                      int S) {
    const int r = blockIdx.x & 7;
    const int sl = blockIdx.x >> 3;
    const int n8 = (N + 7) >> 3;
    const int lo = r * n8, hi = min(N, lo + n8);
    for (int e = sl * 256 + (int)threadIdx.x; e < E; e += S * 256) {
        int d = ei[E + e];
        if (d >= lo && d < hi) {
            int pos = row_ptr[d] + atomicAdd(&cursor[d], 1);
            colarr[pos] = ei[e];
        }
    }
}

// ---------------- node GEMM: Y[N, ldc] = X[N,128] @ Wt^T + epilogue (MFMA fp16) -------------
__global__ __launch_bounds__(256) void gemm_node(const f16_t* __restrict__ X,
                                                 const f16_t* __restrict__ Wt,
                                                 const float* __restrict__ bias,
                                                 const float* __restrict__ bias2,
                                                 const float* __restrict__ rowscale,
                                                 f16_t* __restrict__ Y, int N, int ldc,
                                                 int relu_flag) {
    const int coloff = blockIdx.y * 128;
    __shared__ f16_t sX[128 * 128];
    __shared__ f16_t sW[128 * 128];
    const int tid = threadIdx.x;
    const int row0 = blockIdx.x * 128;
#pragma unroll
    for (int it = 0; it < 8; ++it) {
        int idx = tid + it * 256;
        int r = idx >> 4, c8 = idx & 15;
        int gr = row0 + r;
        uint4 v = make_uint4(0, 0, 0, 0);
        if (gr < N) v = *(const uint4*)(X + (size_t)gr * 128 + c8 * 8);
        *(uint4*)(&sX[r * 128 + (c8 ^ (r & 7)) * 8]) = v;
    }
#pragma unroll
    for (int it = 0; it < 8; ++it) {
        int idx = tid + it * 256;
        int r = idx >> 4, c8 = idx & 15;
        uint4 v = *(const uint4*)(Wt + (size_t)(coloff + r) * 128 + c8 * 8);
        *(uint4*)(&sW[r * 128 + (c8 ^ (r & 7)) * 8]) = v;
    }
    __syncthreads();
    const int wave = tid >> 6, lane = tid & 63;
    const int m = lane & 15, q = lane >> 4;
    const int sw = m & 7;
    f32x4 acc[2][8];
#pragma unroll
    for (int rt = 0; rt < 2; ++rt)
#pragma unroll
        for (int t = 0; t < 8; ++t) acc[rt][t] = (f32x4){0.f, 0.f, 0.f, 0.f};
#pragma unroll
    for (int kk = 0; kk < 4; ++kk) {
        const int g = (kk * 4 + q) ^ sw;
        f16x8 a0 = *(const f16x8*)(&sX[(wave * 32 + m) * 128 + g * 8]);
        f16x8 a1 = *(const f16x8*)(&sX[(wave * 32 + 16 + m) * 128 + g * 8]);
#pragma unroll
        for (int t = 0; t < 8; ++t) {
            f16x8 bfr = *(const f16x8*)(&sW[(t * 16 + m) * 128 + g * 8]);
            acc[0][t] = __builtin_amdgcn_mfma_f32_16x16x32_f16(a0, bfr, acc[0][t], 0, 0, 0);
            acc[1][t] = __builtin_amdgcn_mfma_f32_16x16x32_f16(a1, bfr, acc[1][t], 0, 0, 0);
        }
    }
#pragma unroll
    for (int t = 0; t < 8; ++t) {
        int col = coloff + t * 16 + m;
        float bv = bias ? bias[col] : 0.f;
        float b2v = bias2 ? bias2[col] : 0.f;
#pragma unroll
        for (int rt = 0; rt < 2; ++rt) {
#pragma unroll
            for (int j = 0; j < 4; ++j) {
                int r = row0 + wave * 32 + rt * 16 + q * 4 + j;
                if (r < N) {
                    float v = acc[rt][t][j] + bv;
                    if (rowscale) v += rowscale[r] * b2v;
                    if (relu_flag) v = fmaxf(v, 0.f);
                    Y[(size_t)r * ldc + col] = (f16_t)v;
                }
            }
        }
    }
}

// ---------------- edge aggregation: packed fp16, 8 edges in flight per wave ----------------
// ab: [N,256] f16 = [N,32] uint4; a = uint4 0..15, b = uint4 16..31 of each row.
// Wave per node; lane group g=lane>>4 handles edge slots e+g and e+4+g; lane-in-group l
// covers 8 cols via one uint4. Accumulate in packed fp16; butterfly over groups at the end.
__global__ __launch_bounds__(256) void gather_kernel(const f16_t* __restrict__ ab,
                                                     const int* __restrict__ row_ptr,
                                                     const int* __restrict__ colarr,
                                                     f16_t* __restrict__ q, int N) {
    int wid = (blockIdx.x * 256 + threadIdx.x) >> 6;
    int lane = threadIdx.x & 63;
    if (wid >= N) return;
    const uint4* abu4 = (const uint4*)ab;
    const int g = lane >> 4, l = lane & 15;
    uint4 A = abu4[(size_t)wid * 32 + l];
    f16x2 a0 = __builtin_bit_cast(f16x2, A.x), a1 = __builtin_bit_cast(f16x2, A.y);
    f16x2 a2 = __builtin_bit_cast(f16x2, A.z), a3 = __builtin_bit_cast(f16x2, A.w);
    f16x2 c0 = (f16x2)0, c1 = (f16x2)0, c2 = (f16x2)0, c3 = (f16x2)0;
    if (g == 0) {  // self loop, counted once
        uint4 B = abu4[(size_t)wid * 32 + 16 + l];
        c0 = relu_add2(a0, __builtin_bit_cast(f16x2, B.x));
        c1 = relu_add2(a1, __builtin_bit_cast(f16x2, B.y));
        c2 = relu_add2(a2, __builtin_bit_cast(f16x2, B.z));
        c3 = relu_add2(a3, __builtin_bit_cast(f16x2, B.w));
    }
    int e0 = row_ptr[wid], e1 = row_ptr[wid + 1];
    for (int e = e0; e < e1; e += 8) {
        int i0 = e + g, i1 = e + 4 + g;
        if (i0 < e1) {
            int src = colarr[i0];
            uint4 B = abu4[(size_t)src * 32 + 16 + l];
            c0 += relu_add2(a0, __builtin_bit_cast(f16x2, B.x));
            c1 += relu_add2(a1, __builtin_bit_cast(f16x2, B.y));
            c2 += relu_add2(a2, __builtin_bit_cast(f16x2, B.z));
            c3 += relu_add2(a3, __builtin_bit_cast(f16x2, B.w));
        }
        if (i1 < e1) {
            int src = colarr[i1];
            uint4 B = abu4[(size_t)src * 32 + 16 + l];
            c0 += relu_add2(a0, __builtin_bit_cast(f16x2, B.x));
            c1 += relu_add2(a1, __builtin_bit_cast(f16x2, B.y));
            c2 += relu_add2(a2, __builtin_bit_cast(f16x2, B.z));
            c3 += relu_add2(a3, __builtin_bit_cast(f16x2, B.w));
        }
    }
    // sum across the 4 groups (packed fp16 adds on shuffled u32)
#pragma unroll
    for (int off = 16; off < 64; off <<= 1) {
        c0 += __builtin_bit_cast(f16x2, __shfl_xor(__builtin_bit_cast(int, c0), off));
        c1 += __builtin_bit_cast(f16x2, __shfl_xor(__builtin_bit_cast(int, c1), off));
        c2 += __builtin_bit_cast(f16x2, __shfl_xor(__builtin_bit_cast(int, c2), off));
        c3 += __builtin_bit_cast(f16x2, __shfl_xor(__builtin_bit_cast(int, c3), off));
    }
    if (g == 0) {
        uint4 o;
        o.x = __builtin_bit_cast(u32, c0);
        o.y = __builtin_bit_cast(u32, c1);
        o.z = __builtin_bit_cast(u32, c2);
        o.w = __builtin_bit_cast(u32, c3);
        ((uint4*)q)[(size_t)wid * 16 + l] = o;
    }
}

// ---------------- pooling ----------------
__global__ __launch_bounds__(256) void pool_kernel(const f16_t* __restrict__ agg,
                                                   const int* __restrict__ batch,
                                                   float* __restrict__ pooled,
                                                   int* __restrict__ cntg, int N) {
    int wid = (blockIdx.x * 256 + threadIdx.x) >> 6;
    int lane = threadIdx.x & 63;
    int n0 = wid * 32;
    if (n0 >= N) return;
    int n1 = min(n0 + 32, N);
    const u32* au = (const u32*)agg;
    int gcur = batch[n0];
    float sx = 0.f, sy = 0.f;
    int cnt = 0;
    for (int n = n0; n < n1; ++n) {
        int g = batch[n];
        if (g != gcur) {
            atomicAdd(&pooled[gcur * 128 + lane * 2], sx);
            atomicAdd(&pooled[gcur * 128 + lane * 2 + 1], sy);
            if (lane == 0) atomicAdd(&cntg[gcur], cnt);
            gcur = g; sx = 0.f; sy = 0.f; cnt = 0;
        }
        u32 v = au[(size_t)n * 64 + lane];
        sx += f16lo(v);
        sy += f16hi(v);
        ++cnt;
    }
    atomicAdd(&pooled[gcur * 128 + lane * 2], sx);
    atomicAdd(&pooled[gcur * 128 + lane * 2 + 1], sy);
    if (lane == 0) atomicAdd(&cntg[gcur], cnt);
}

// ---------------- final ----------------
__global__ __launch_bounds__(256) void final_kernel(const float* __restrict__ pooled,
                                                    const int* __restrict__ cntg,
                                                    const float* __restrict__ out_w,
                                                    const float* __restrict__ out_b,
                                                    float* __restrict__ out, int total) {
    int idx = blockIdx.x * 256 + threadIdx.x;
    if (idx >= total) return;
    int g = idx >> 6, o = idx & 63;
    float c = fmaxf((float)cntg[g], 1.0f);
    float s = 0.f;
#pragma unroll 4
    for (int k = 0; k < 128; ++k) s += pooled[g * 128 + k] * out_w[k * 64 + o];
    out[idx] = s / c + out_b[o];
}

extern "C" void kernel_launch(void* const* d_in, const int* in_sizes, int n_in, void* d_out,
                              int out_size, void* d_ws, size_t ws_size, hipStream_t stream) {
    const float* x = (const float*)d_in[0];
    const int* ei = (const int*)d_in[1];
    const int* batch = (const int*)d_in[3];
    const float* cw[3][6];  // lin_w, lin_b, w1, b1, w2, b2
    for (int l = 0; l < 3; ++l)
        for (int j = 0; j < 6; ++j) cw[l][j] = (const float*)d_in[4 + l * 6 + j];
    const float* out_w = (const float*)d_in[22];
    const float* out_b = (const float*)d_in[23];
    float* out = (float*)d_out;

    const int N = in_sizes[0] / 128;
    const int E = in_sizes[1] / 2;
    const int G = out_size / 64;

    // ---- workspace layout ----
    char* base = (char*)d_ws;
    size_t off = 0;
    auto alloc = [&](size_t b) { size_t o = off; off += (b + 255) & ~(size_t)255; return o; };
    int* deg = (int*)(base + alloc((size_t)N * 4));
    int* cursor = (int*)(base + alloc((size_t)N * 4));
    float* pooled = (float*)(base + alloc((size_t)G * 128 * 4));
    int* cntg = (int*)(base + alloc((size_t)G * 4));
    const size_t zero_bytes = off;
    int* row_ptr = (int*)(base + alloc((size_t)(N + 1) * 4));
    float* cntp1f = (float*)(base + alloc((size_t)N * 4));
    int* colarr = (int*)(base + alloc((size_t)E * 4));
    int* bsum = (int*)(base + alloc(256 * 4));
    f16_t* xb = (f16_t*)(base + alloc((size_t)N * 128 * 2));  // layer input / agg output
    f16_t* q = (f16_t*)(base + alloc((size_t)N * 128 * 2));   // gather output
    f16_t* ab = (f16_t*)(base + alloc((size_t)N * 256 * 2));  // [a|b]
    f16_t* W12ct[3]; f16_t* W2t[3]; float* bias256c[3];
    for (int l = 0; l < 3; ++l) {
        W12ct[l] = (f16_t*)(base + alloc(32768 * 2));
        W2t[l] = (f16_t*)(base + alloc(16384 * 2));
        bias256c[l] = (float*)(base + alloc(256 * 4));
    }
    (void)ws_size; (void)n_in;

    hipMemsetAsync(d_ws, 0, zero_bytes, stream);

    // prep
    convx_kernel<<<(N * 128 / 4 + 255) / 256, 256, 0, stream>>>(x, xb, N * 128);
    for (int l = 0; l < 3; ++l)
        prepw_kernel<<<194, 256, 0, stream>>>(cw[l][0], cw[l][1], cw[l][2], cw[l][3], cw[l][4],
                                              W12ct[l], W2t[l], bias256c[l]);
    // CSR
    const int nb = (N + 1023) / 1024;
    deg_kernel<<<(E + 255) / 256, 256, 0, stream>>>(ei, deg, E);
    scan_pass1<<<nb, 256, 0, stream>>>(deg, bsum, N);
    scan_pass2<<<1, 256, 0, stream>>>(bsum, nb);
    scan_pass3<<<nb, 256, 0, stream>>>(deg, bsum, row_ptr, cntp1f, N);
    const int S = 96;
    scatter_kernel<<<8 * S, 256, 0, stream>>>(ei, row_ptr, cursor, colarr, E, N, S);

    const int gblocks = (N + 127) / 128;
    auto gemm = [&](const f16_t* X, const f16_t* Wt, const float* bias, const float* bias2,
                    const float* rowscale, f16_t* Y, int ncol, int relu_flag) {
        gemm_node<<<dim3(gblocks, ncol / 128), 256, 0, stream>>>(X, Wt, bias, bias2, rowscale, Y,
                                                                 N, ncol, relu_flag);
    };

    const f16_t* Xin = xb;
    for (int l = 0; l < 3; ++l) {
        gemm(Xin, W12ct[l], bias256c[l], nullptr, nullptr, ab, 256, 0);
        gather_kernel<<<(N * 64 + 255) / 256, 256, 0, stream>>>(ab, row_ptr, colarr, q, N);
        gemm(q, W2t[l], nullptr, cw[l][5], cntp1f, xb, 128, 1);
        Xin = xb;
    }

    pool_kernel<<<((N + 31) / 32 * 64 + 255) / 256, 256, 0, stream>>>(Xin, batch, pooled, cntg, N);
    final_kernel<<<(G * 64 + 255) / 256, 256, 0, stream>>>(pooled, cntg, out_w, out_b, out,
                                                           G * 64);
}

// Round 5
// 542.597 us; speedup vs baseline: 1.5772x; 1.0310x over previous
//
#include <hip/hip_runtime.h>
#include <hip/hip_bf16.h>

// MPNN on MI355X.
// Identities used:
//  (1) sum_e relu(a[dst]+b[src]) @ w2 == (sum_e relu(a[dst]+b[src])) @ w2
//  (2) (x@lin_w+lin_b)@w1 == x@(lin_w@w1) + (lin_b@w1)  -> lin GEMM composed into w1 GEMM
// Per layer: ONE 256-col GEMM (composed), gather(edge add+relu+acc), ONE 128-col GEMM (w2).
// Intermediates FP16 (packed v_pk_add/max_f16 in gather).
// CSR build is atomic-free at write time: deg pass records per-edge rank (u8), partition pass
// buckets (addr,src) by addr/bsz (8 buckets ~= XCDs), csr_write scatters within one 400KB
// window per XCD -> writebacks merge in that XCD's L2.

typedef _Float16 f16_t;
typedef f16_t f16x2 __attribute__((ext_vector_type(2)));
typedef f16_t f16x8 __attribute__((ext_vector_type(8)));
typedef float f32x4 __attribute__((ext_vector_type(4)));
typedef unsigned int u32;
typedef unsigned short u16;
typedef unsigned char u8;

__device__ __forceinline__ float f16lo(u32 v) {
    return (float)__builtin_bit_cast(f16_t, (u16)(v & 0xffff));
}
__device__ __forceinline__ float f16hi(u32 v) {
    return (float)__builtin_bit_cast(f16_t, (u16)(v >> 16));
}
__device__ __forceinline__ u32 f16pack(float x, float y) {
    u16 a = __builtin_bit_cast(u16, (f16_t)x);
    u16 b = __builtin_bit_cast(u16, (f16_t)y);
    return (u32)a | ((u32)b << 16);
}
__device__ __forceinline__ f16x2 relu_add2(f16x2 a, f16x2 b) {
    f16x2 s = a + b;                                // v_pk_add_f16
    return __builtin_elementwise_max(s, (f16x2)0);  // v_pk_max_f16
}

// ---------------- fused prep: convx | deg+pos | prepw x3 ----------------
struct PrepArgs {
    const float* x; f16_t* xb; int totalx;
    const int* ei; int* deg; u8* pos; int E;
    const float* lin_w[3]; const float* lin_b[3];
    const float* w1[3]; const float* b1[3]; const float* w2[3];
    f16_t* W12ct; f16_t* W2t; float* bias256c;  // per-layer strides 32768 / 16384 / 256
};

__global__ __launch_bounds__(256) void prep_kernel(PrepArgs A, int nConvB, int nDegB) {
    const int b = blockIdx.x, tid = threadIdx.x;
    if (b < nConvB) {
        int i = (b * 256 + tid) * 4;
        if (i >= A.totalx) return;
        float4 v = *(const float4*)(A.x + i);
        *(uint2*)(A.xb + i) = make_uint2(f16pack(v.x, v.y), f16pack(v.z, v.w));
    } else if (b < nConvB + nDegB) {
        int e = (b - nConvB) * 256 + tid;
        if (e < A.E) A.pos[e] = (u8)atomicAdd(&A.deg[A.ei[A.E + e]], 1);
    } else {
        int pb = b - nConvB - nDegB;
        int layer = pb / 193;
        int idx = (pb % 193) * 256 + tid;
        const float* lin_w = A.lin_w[layer]; const float* lin_b = A.lin_b[layer];
        const float* w1 = A.w1[layer]; const float* b1 = A.b1[layer];
        const float* w2 = A.w2[layer];
        f16_t* W12ct = A.W12ct + layer * 32768;
        f16_t* W2t = A.W2t + layer * 16384;
        float* bias256c = A.bias256c + layer * 256;
        if (idx < 32768) {
            int j = idx >> 7, k = idx & 127;
            const float* wcol = (j < 128) ? (w1 + j) : (w1 + 128 * 128 + (j - 128));
            const float* lrow = lin_w + k * 128;
            float s = 0.f;
#pragma unroll 4
            for (int c = 0; c < 128; ++c) s += lrow[c] * wcol[c * 128];
            W12ct[idx] = (f16_t)s;
        } else if (idx < 32768 + 16384) {
            int i = idx - 32768;
            int j = i >> 7, k = i & 127;
            W2t[i] = (f16_t)w2[k * 128 + j];
        } else if (idx < 32768 + 16384 + 256) {
            int j = idx - 49152;
            const float* wcol = (j < 128) ? (w1 + j) : (w1 + 128 * 128 + (j - 128));
            float s = (j < 128) ? b1[j] : 0.f;
            for (int c = 0; c < 128; ++c) s += lin_b[c] * wcol[c * 128];
            bias256c[j] = s;
        }
    }
}

// ---------------- scan (3-pass hierarchical) ----------------
__global__ __launch_bounds__(256) void scan_pass1(const int* __restrict__ deg,
                                                  int* __restrict__ bsum, int N) {
    __shared__ int red[4];
    int t = threadIdx.x;
    int base = blockIdx.x * 1024 + t * 4;
    int4 v = make_int4(0, 0, 0, 0);
    if (base + 3 < N) v = *(const int4*)(deg + base);
    else {
        if (base + 0 < N) v.x = deg[base + 0];
        if (base + 1 < N) v.y = deg[base + 1];
        if (base + 2 < N) v.z = deg[base + 2];
    }
    int s = v.x + v.y + v.z + v.w;
#pragma unroll
    for (int off = 1; off < 64; off <<= 1) s += __shfl_xor(s, off);
    if ((t & 63) == 0) red[t >> 6] = s;
    __syncthreads();
    if (t == 0) bsum[blockIdx.x] = red[0] + red[1] + red[2] + red[3];
}

__global__ __launch_bounds__(256) void scan_pass2(int* __restrict__ bsum, int nb) {
    __shared__ int sh[256];
    int t = threadIdx.x;
    int v = (t < nb) ? bsum[t] : 0;
    sh[t] = v;
    __syncthreads();
#pragma unroll
    for (int off = 1; off < 256; off <<= 1) {
        int u = (t >= off) ? sh[t - off] : 0;
        __syncthreads();
        sh[t] += u;
        __syncthreads();
    }
    if (t < nb) bsum[t] = sh[t] - v;
}

__global__ __launch_bounds__(256) void scan_pass3(const int* __restrict__ deg,
                                                  const int* __restrict__ bsum,
                                                  int* __restrict__ row_ptr,
                                                  float* __restrict__ cntp1f, int N) {
    __shared__ int sh[256];
    int t = threadIdx.x;
    int base = blockIdx.x * 1024 + t * 4;
    int4 v = make_int4(0, 0, 0, 0);
    if (base + 3 < N) v = *(const int4*)(deg + base);
    else {
        if (base + 0 < N) v.x = deg[base + 0];
        if (base + 1 < N) v.y = deg[base + 1];
        if (base + 2 < N) v.z = deg[base + 2];
    }
    int s = v.x + v.y + v.z + v.w;
    sh[t] = s;
    __syncthreads();
#pragma unroll
    for (int off = 1; off < 256; off <<= 1) {
        int u = (t >= off) ? sh[t - off] : 0;
        __syncthreads();
        sh[t] += u;
        __syncthreads();
    }
    int pre = sh[t] - s + bsum[blockIdx.x];
    int vv[4] = {v.x, v.y, v.z, v.w};
#pragma unroll
    for (int i = 0; i < 4; ++i) {
        int idx = base + i;
        if (idx < N) {
            row_ptr[idx] = pre;
            cntp1f[idx] = (float)(vv[i] + 1);
            pre += vv[i];
            if (idx == N - 1) row_ptr[N] = pre;
        }
    }
}

// ---------------- partition: bucket (addr,src) by addr/bsz, block-aggregated append --------
__global__ __launch_bounds__(256) void part_kernel(const int* __restrict__ ei,
                                                   const u8* __restrict__ pos,
                                                   const int* __restrict__ row_ptr,
                                                   int* __restrict__ bcnt,
                                                   int2* __restrict__ bbuf, int E, int bsz) {
    __shared__ int cnt[4][8];
    __shared__ int baseb[8];
    int tid = threadIdx.x, lane = tid & 63, w = tid >> 6;
    int e = blockIdx.x * 256 + tid;
    int bkt = -1, addr = 0, src = 0;
    if (e < E) {
        int dst = ei[E + e];
        src = ei[e];
        addr = row_ptr[dst] + (int)pos[e];
        bkt = addr / bsz;
    }
    int myrank = 0;
#pragma unroll
    for (int b = 0; b < 8; ++b) {
        unsigned long long m = __ballot(bkt == b);
        if (lane == b) cnt[w][b] = (int)__popcll(m);  // lane b records count for bucket b
        if (bkt == b) myrank = (int)__popcll(m & ((1ull << lane) - 1ull));
    }
    __syncthreads();
    if (tid < 8) {
        int t = 0;
#pragma unroll
        for (int ww = 0; ww < 4; ++ww) { int c = cnt[ww][tid]; cnt[ww][tid] = t; t += c; }
        baseb[tid] = t ? atomicAdd(&bcnt[tid], t) : 0;
    }
    __syncthreads();
    if (bkt >= 0) {
        int p = baseb[bkt] + cnt[w][bkt] + myrank;
        bbuf[(size_t)bkt * bsz + p] = make_int2(addr, src);
    }
}

// ---------------- csr write: bucket = blockIdx&7 (XCD-local window), atomic-free -----------
__global__ __launch_bounds__(256) void csr_write(const int2* __restrict__ bbuf,
                                                 const int* __restrict__ bcnt,
                                                 int* __restrict__ colarr, int bsz, int S2) {
    int bkt = blockIdx.x & 7, sl = blockIdx.x >> 3;
    int cnt = bcnt[bkt];
    const int2* src = bbuf + (size_t)bkt * bsz;
    for (int i = sl * 256 + (int)threadIdx.x; i < cnt; i += S2 * 256) {
        int2 en = src[i];
        colarr[en.x] = en.y;
    }
}

// ---------------- node GEMM: Y[N, ldc] = X[N,128] @ Wt^T + epilogue (MFMA fp16) ------------
__global__ __launch_bounds__(256) void gemm_node(const f16_t* __restrict__ X,
                                                 const f16_t* __restrict__ Wt,
                                                 const float* __restrict__ bias,
                                                 const float* __restrict__ bias2,
                                                 const float* __restrict__ rowscale,
                                                 f16_t* __restrict__ Y, int N, int ldc,
                                                 int relu_flag) {
    const int coloff = blockIdx.y * 128;
    __shared__ f16_t sX[128 * 128];
    __shared__ f16_t sW[128 * 128];
    const int tid = threadIdx.x;
    const int row0 = blockIdx.x * 128;
#pragma unroll
    for (int it = 0; it < 8; ++it) {
        int idx = tid + it * 256;
        int r = idx >> 4, c8 = idx & 15;
        int gr = row0 + r;
        uint4 v = make_uint4(0, 0, 0, 0);
        if (gr < N) v = *(const uint4*)(X + (size_t)gr * 128 + c8 * 8);
        *(uint4*)(&sX[r * 128 + (c8 ^ (r & 7)) * 8]) = v;
    }
#pragma unroll
    for (int it = 0; it < 8; ++it) {
        int idx = tid + it * 256;
        int r = idx >> 4, c8 = idx & 15;
        uint4 v = *(const uint4*)(Wt + (size_t)(coloff + r) * 128 + c8 * 8);
        *(uint4*)(&sW[r * 128 + (c8 ^ (r & 7)) * 8]) = v;
    }
    __syncthreads();
    const int wave = tid >> 6, lane = tid & 63;
    const int m = lane & 15, q = lane >> 4;
    const int sw = m & 7;
    f32x4 acc[2][8];
#pragma unroll
    for (int rt = 0; rt < 2; ++rt)
#pragma unroll
        for (int t = 0; t < 8; ++t) acc[rt][t] = (f32x4){0.f, 0.f, 0.f, 0.f};
#pragma unroll
    for (int kk = 0; kk < 4; ++kk) {
        const int g = (kk * 4 + q) ^ sw;
        f16x8 a0 = *(const f16x8*)(&sX[(wave * 32 + m) * 128 + g * 8]);
        f16x8 a1 = *(const f16x8*)(&sX[(wave * 32 + 16 + m) * 128 + g * 8]);
#pragma unroll
        for (int t = 0; t < 8; ++t) {
            f16x8 bfr = *(const f16x8*)(&sW[(t * 16 + m) * 128 + g * 8]);
            acc[0][t] = __builtin_amdgcn_mfma_f32_16x16x32_f16(a0, bfr, acc[0][t], 0, 0, 0);
            acc[1][t] = __builtin_amdgcn_mfma_f32_16x16x32_f16(a1, bfr, acc[1][t], 0, 0, 0);
        }
    }
#pragma unroll
    for (int t = 0; t < 8; ++t) {
        int col = coloff + t * 16 + m;
        float bv = bias ? bias[col] : 0.f;
        float b2v = bias2 ? bias2[col] : 0.f;
#pragma unroll
        for (int rt = 0; rt < 2; ++rt) {
#pragma unroll
            for (int j = 0; j < 4; ++j) {
                int r = row0 + wave * 32 + rt * 16 + q * 4 + j;
                if (r < N) {
                    float v = acc[rt][t][j] + bv;
                    if (rowscale) v += rowscale[r] * b2v;
                    if (relu_flag) v = fmaxf(v, 0.f);
                    Y[(size_t)r * ldc + col] = (f16_t)v;
                }
            }
        }
    }
}

// ---------------- edge aggregation: packed fp16, 16 edges in flight per wave ----------------
__global__ __launch_bounds__(256) void gather_kernel(const f16_t* __restrict__ ab,
                                                     const int* __restrict__ row_ptr,
                                                     const int* __restrict__ colarr,
                                                     f16_t* __restrict__ q, int N) {
    int wid = (blockIdx.x * 256 + threadIdx.x) >> 6;
    int lane = threadIdx.x & 63;
    if (wid >= N) return;
    const uint4* abu4 = (const uint4*)ab;
    const int g = lane >> 4, l = lane & 15;
    uint4 A = abu4[(size_t)wid * 32 + l];
    f16x2 a0 = __builtin_bit_cast(f16x2, A.x), a1 = __builtin_bit_cast(f16x2, A.y);
    f16x2 a2 = __builtin_bit_cast(f16x2, A.z), a3 = __builtin_bit_cast(f16x2, A.w);
    f16x2 c0 = (f16x2)0, c1 = (f16x2)0, c2 = (f16x2)0, c3 = (f16x2)0;
    if (g == 0) {  // self loop, counted once
        uint4 B = abu4[(size_t)wid * 32 + 16 + l];
        c0 = relu_add2(a0, __builtin_bit_cast(f16x2, B.x));
        c1 = relu_add2(a1, __builtin_bit_cast(f16x2, B.y));
        c2 = relu_add2(a2, __builtin_bit_cast(f16x2, B.z));
        c3 = relu_add2(a3, __builtin_bit_cast(f16x2, B.w));
    }
    int e0 = row_ptr[wid], e1 = row_ptr[wid + 1];
    int e = e0;
    // main loop: 16 edges in flight (4 slots/group)
    for (; e + 16 <= e1; e += 16) {
        int s0 = colarr[e + g], s1 = colarr[e + 4 + g];
        int s2 = colarr[e + 8 + g], s3 = colarr[e + 12 + g];
        uint4 B0 = abu4[(size_t)s0 * 32 + 16 + l];
        uint4 B1 = abu4[(size_t)s1 * 32 + 16 + l];
        uint4 B2 = abu4[(size_t)s2 * 32 + 16 + l];
        uint4 B3 = abu4[(size_t)s3 * 32 + 16 + l];
        c0 += relu_add2(a0, __builtin_bit_cast(f16x2, B0.x));
        c1 += relu_add2(a1, __builtin_bit_cast(f16x2, B0.y));
        c2 += relu_add2(a2, __builtin_bit_cast(f16x2, B0.z));
        c3 += relu_add2(a3, __builtin_bit_cast(f16x2, B0.w));
        c0 += relu_add2(a0, __builtin_bit_cast(f16x2, B1.x));
        c1 += relu_add2(a1, __builtin_bit_cast(f16x2, B1.y));
        c2 += relu_add2(a2, __builtin_bit_cast(f16x2, B1.z));
        c3 += relu_add2(a3, __builtin_bit_cast(f16x2, B1.w));
        c0 += relu_add2(a0, __builtin_bit_cast(f16x2, B2.x));
        c1 += relu_add2(a1, __builtin_bit_cast(f16x2, B2.y));
        c2 += relu_add2(a2, __builtin_bit_cast(f16x2, B2.z));
        c3 += relu_add2(a3, __builtin_bit_cast(f16x2, B2.w));
        c0 += relu_add2(a0, __builtin_bit_cast(f16x2, B3.x));
        c1 += relu_add2(a1, __builtin_bit_cast(f16x2, B3.y));
        c2 += relu_add2(a2, __builtin_bit_cast(f16x2, B3.z));
        c3 += relu_add2(a3, __builtin_bit_cast(f16x2, B3.w));
    }
    // tail: 4 edges at a time
    for (; e < e1; e += 4) {
        int i0 = e + g;
        if (i0 < e1) {
            int src = colarr[i0];
            uint4 B = abu4[(size_t)src * 32 + 16 + l];
            c0 += relu_add2(a0, __builtin_bit_cast(f16x2, B.x));
            c1 += relu_add2(a1, __builtin_bit_cast(f16x2, B.y));
            c2 += relu_add2(a2, __builtin_bit_cast(f16x2, B.z));
            c3 += relu_add2(a3, __builtin_bit_cast(f16x2, B.w));
        }
    }
#pragma unroll
    for (int off = 16; off < 64; off <<= 1) {
        c0 += __builtin_bit_cast(f16x2, __shfl_xor(__builtin_bit_cast(int, c0), off));
        c1 += __builtin_bit_cast(f16x2, __shfl_xor(__builtin_bit_cast(int, c1), off));
        c2 += __builtin_bit_cast(f16x2, __shfl_xor(__builtin_bit_cast(int, c2), off));
        c3 += __builtin_bit_cast(f16x2, __shfl_xor(__builtin_bit_cast(int, c3), off));
    }
    if (g == 0) {
        uint4 o;
        o.x = __builtin_bit_cast(u32, c0);
        o.y = __builtin_bit_cast(u32, c1);
        o.z = __builtin_bit_cast(u32, c2);
        o.w = __builtin_bit_cast(u32, c3);
        ((uint4*)q)[(size_t)wid * 16 + l] = o;
    }
}

// ---------------- pooling ----------------
__global__ __launch_bounds__(256) void pool_kernel(const f16_t* __restrict__ agg,
                                                   const int* __restrict__ batch,
                                                   float* __restrict__ pooled,
                                                   int* __restrict__ cntg, int N) {
    int wid = (blockIdx.x * 256 + threadIdx.x) >> 6;
    int lane = threadIdx.x & 63;
    int n0 = wid * 32;
    if (n0 >= N) return;
    int n1 = min(n0 + 32, N);
    const u32* au = (const u32*)agg;
    int gcur = batch[n0];
    float sx = 0.f, sy = 0.f;
    int cnt = 0;
    for (int n = n0; n < n1; ++n) {
        int g = batch[n];
        if (g != gcur) {
            atomicAdd(&pooled[gcur * 128 + lane * 2], sx);
            atomicAdd(&pooled[gcur * 128 + lane * 2 + 1], sy);
            if (lane == 0) atomicAdd(&cntg[gcur], cnt);
            gcur = g; sx = 0.f; sy = 0.f; cnt = 0;
        }
        u32 v = au[(size_t)n * 64 + lane];
        sx += f16lo(v);
        sy += f16hi(v);
        ++cnt;
    }
    atomicAdd(&pooled[gcur * 128 + lane * 2], sx);
    atomicAdd(&pooled[gcur * 128 + lane * 2 + 1], sy);
    if (lane == 0) atomicAdd(&cntg[gcur], cnt);
}

// ---------------- final ----------------
__global__ __launch_bounds__(256) void final_kernel(const float* __restrict__ pooled,
                                                    const int* __restrict__ cntg,
                                                    const float* __restrict__ out_w,
                                                    const float* __restrict__ out_b,
                                                    float* __restrict__ out, int total) {
    int idx = blockIdx.x * 256 + threadIdx.x;
    if (idx >= total) return;
    int g = idx >> 6, o = idx & 63;
    float c = fmaxf((float)cntg[g], 1.0f);
    float s = 0.f;
#pragma unroll 4
    for (int k = 0; k < 128; ++k) s += pooled[g * 128 + k] * out_w[k * 64 + o];
    out[idx] = s / c + out_b[o];
}

extern "C" void kernel_launch(void* const* d_in, const int* in_sizes, int n_in, void* d_out,
                              int out_size, void* d_ws, size_t ws_size, hipStream_t stream) {
    const float* x = (const float*)d_in[0];
    const int* ei = (const int*)d_in[1];
    const int* batch = (const int*)d_in[3];
    const float* cw[3][6];  // lin_w, lin_b, w1, b1, w2, b2
    for (int l = 0; l < 3; ++l)
        for (int j = 0; j < 6; ++j) cw[l][j] = (const float*)d_in[4 + l * 6 + j];
    const float* out_w = (const float*)d_in[22];
    const float* out_b = (const float*)d_in[23];
    float* out = (float*)d_out;

    const int N = in_sizes[0] / 128;
    const int E = in_sizes[1] / 2;
    const int G = out_size / 64;
    const int bsz = (E + 7) / 8;

    // ---- workspace layout ----
    char* base = (char*)d_ws;
    size_t off = 0;
    auto alloc = [&](size_t b) { size_t o = off; off += (b + 255) & ~(size_t)255; return o; };
    int* deg = (int*)(base + alloc((size_t)N * 4));
    float* pooled = (float*)(base + alloc((size_t)G * 128 * 4));
    int* cntg = (int*)(base + alloc((size_t)G * 4));
    int* bcnt = (int*)(base + alloc(8 * 4));
    const size_t zero_bytes = off;
    int* row_ptr = (int*)(base + alloc((size_t)(N + 1) * 4));
    float* cntp1f = (float*)(base + alloc((size_t)N * 4));
    int* colarr = (int*)(base + alloc((size_t)E * 4));
    u8* pos = (u8*)(base + alloc((size_t)E));
    int2* bbuf = (int2*)(base + alloc((size_t)8 * bsz * 8));
    int* bsum = (int*)(base + alloc(256 * 4));
    f16_t* xb = (f16_t*)(base + alloc((size_t)N * 128 * 2));  // layer input / agg output
    f16_t* q = (f16_t*)(base + alloc((size_t)N * 128 * 2));   // gather output
    f16_t* ab = (f16_t*)(base + alloc((size_t)N * 256 * 2));  // [a|b]
    f16_t* W12ct = (f16_t*)(base + alloc(3 * 32768 * 2));
    f16_t* W2t = (f16_t*)(base + alloc(3 * 16384 * 2));
    float* bias256c = (float*)(base + alloc(3 * 256 * 4));
    (void)ws_size; (void)n_in;

    hipMemsetAsync(d_ws, 0, zero_bytes, stream);

    // fused prep: convx | deg+pos | prepw x3
    PrepArgs pa;
    pa.x = x; pa.xb = xb; pa.totalx = N * 128;
    pa.ei = ei; pa.deg = deg; pa.pos = pos; pa.E = E;
    for (int l = 0; l < 3; ++l) {
        pa.lin_w[l] = cw[l][0]; pa.lin_b[l] = cw[l][1];
        pa.w1[l] = cw[l][2]; pa.b1[l] = cw[l][3]; pa.w2[l] = cw[l][4];
    }
    pa.W12ct = W12ct; pa.W2t = W2t; pa.bias256c = bias256c;
    const int nConvB = (N * 128 / 4 + 255) / 256;
    const int nDegB = (E + 255) / 256;
    prep_kernel<<<nConvB + nDegB + 3 * 193, 256, 0, stream>>>(pa, nConvB, nDegB);

    // CSR
    const int nb = (N + 1023) / 1024;
    scan_pass1<<<nb, 256, 0, stream>>>(deg, bsum, N);
    scan_pass2<<<1, 256, 0, stream>>>(bsum, nb);
    scan_pass3<<<nb, 256, 0, stream>>>(deg, bsum, row_ptr, cntp1f, N);
    part_kernel<<<(E + 255) / 256, 256, 0, stream>>>(ei, pos, row_ptr, bcnt, bbuf, E, bsz);
    const int S2 = 32;
    csr_write<<<8 * S2, 256, 0, stream>>>(bbuf, bcnt, colarr, bsz, S2);

    const int gblocks = (N + 127) / 128;
    auto gemm = [&](const f16_t* X, const f16_t* Wt, const float* bias, const float* bias2,
                    const float* rowscale, f16_t* Y, int ncol, int relu_flag) {
        gemm_node<<<dim3(gblocks, ncol / 128), 256, 0, stream>>>(X, Wt, bias, bias2, rowscale, Y,
                                                                 N, ncol, relu_flag);
    };

    const f16_t* Xin = xb;
    for (int l = 0; l < 3; ++l) {
        gemm(Xin, W12ct + l * 32768, bias256c + l * 256, nullptr, nullptr, ab, 256, 0);
        gather_kernel<<<(N * 64 + 255) / 256, 256, 0, stream>>>(ab, row_ptr, colarr, q, N);
        gemm(q, W2t + l * 16384, nullptr, cw[l][5], cntp1f, xb, 128, 1);
        Xin = xb;
    }

    pool_kernel<<<((N + 31) / 32 * 64 + 255) / 256, 256, 0, stream>>>(Xin, batch, pooled, cntg, N);
    final_kernel<<<(G * 64 + 255) / 256, 256, 0, stream>>>(pooled, cntg, out_w, out_b, out,
                                                           G * 64);
}

// Round 6
// 508.533 us; speedup vs baseline: 1.6828x; 1.0670x over previous
//
#include <hip/hip_runtime.h>
#include <hip/hip_bf16.h>

// MPNN on MI355X.
// Identities used:
//  (1) sum_e relu(a[dst]+b[src]) @ w2 == (sum_e relu(a[dst]+b[src])) @ w2
//  (2) (x@lin_w+lin_b)@w1 == x@(lin_w@w1) + (lin_b@w1)  -> lin GEMM composed into w1 GEMM
// Per layer: ONE 256-col GEMM (composed), gather(edge add+relu+acc), ONE 128-col GEMM (w2).
// Intermediates FP16 (packed v_pk_add/max_f16 in gather).
// CSR build: bucketed counting sort. Bucket by dst>>8 (256 nodes/bucket) with block-local LDS
// histograms; per-bucket blocks count degree and scatter via LDS returning atomics (cheap),
// colarr writes stay in a contiguous ~16KB window per bucket -> writebacks merge. NO global
// value-returning atomics on the per-edge path (R5's 66us prep regression was exactly that).

typedef _Float16 f16_t;
typedef f16_t f16x2 __attribute__((ext_vector_type(2)));
typedef f16_t f16x8 __attribute__((ext_vector_type(8)));
typedef float f32x4 __attribute__((ext_vector_type(4)));
typedef unsigned int u32;
typedef unsigned short u16;
typedef unsigned char u8;

__device__ __forceinline__ float f16lo(u32 v) {
    return (float)__builtin_bit_cast(f16_t, (u16)(v & 0xffff));
}
__device__ __forceinline__ float f16hi(u32 v) {
    return (float)__builtin_bit_cast(f16_t, (u16)(v >> 16));
}
__device__ __forceinline__ u32 f16pack(float x, float y) {
    u16 a = __builtin_bit_cast(u16, (f16_t)x);
    u16 b = __builtin_bit_cast(u16, (f16_t)y);
    return (u32)a | ((u32)b << 16);
}
__device__ __forceinline__ f16x2 relu_add2(f16x2 a, f16x2 b) {
    f16x2 s = a + b;                                // v_pk_add_f16
    return __builtin_elementwise_max(s, (f16x2)0);  // v_pk_max_f16
}

// ---------------- fused prep: convx | prepw x3 | edge bucketing ----------------
struct PrepArgs {
    const float* x; f16_t* xb; int totalx;
    const int* ei; int E;
    int* bcnt; int2* bbuf; int cap; int nBktB;
    const float* lin_w[3]; const float* lin_b[3];
    const float* w1[3]; const float* b1[3]; const float* w2[3];
    f16_t* W12ct; f16_t* W2t; float* bias256c;  // per-layer strides 32768 / 16384 / 256
};

__global__ __launch_bounds__(256) void prep_kernel(PrepArgs A, int nConvB) {
    const int b = blockIdx.x, tid = threadIdx.x;
    if (b < nConvB) {
        int i = (b * 256 + tid) * 4;
        if (i >= A.totalx) return;
        float4 v = *(const float4*)(A.x + i);
        *(uint2*)(A.xb + i) = make_uint2(f16pack(v.x, v.y), f16pack(v.z, v.w));
        return;
    }
    int pb = b - nConvB;
    if (pb < 3 * 193) {
        int layer = pb / 193;
        int idx = (pb % 193) * 256 + tid;
        const float* lin_w = A.lin_w[layer]; const float* lin_b = A.lin_b[layer];
        const float* w1 = A.w1[layer]; const float* b1 = A.b1[layer];
        const float* w2 = A.w2[layer];
        f16_t* W12ct = A.W12ct + layer * 32768;
        f16_t* W2t = A.W2t + layer * 16384;
        float* bias256c = A.bias256c + layer * 256;
        if (idx < 32768) {
            int j = idx >> 7, k = idx & 127;
            const float* wcol = (j < 128) ? (w1 + j) : (w1 + 128 * 128 + (j - 128));
            const float* lrow = lin_w + k * 128;
            float s = 0.f;
#pragma unroll 4
            for (int c = 0; c < 128; ++c) s += lrow[c] * wcol[c * 128];
            W12ct[idx] = (f16_t)s;
        } else if (idx < 32768 + 16384) {
            int i = idx - 32768;
            int j = i >> 7, k = i & 127;
            W2t[i] = (f16_t)w2[k * 128 + j];
        } else if (idx < 32768 + 16384 + 256) {
            int j = idx - 49152;
            const float* wcol = (j < 128) ? (w1 + j) : (w1 + 128 * 128 + (j - 128));
            float s = (j < 128) ? b1[j] : 0.f;
            for (int c = 0; c < 128; ++c) s += lin_b[c] * wcol[c * 128];
            bias256c[j] = s;
        }
        return;
    }
    // ---- edge bucketing: bucket = dst>>8 ----
    int bb = pb - 3 * 193;
    __shared__ int cnt[256];
    __shared__ int basep[256];
    const int E = A.E;
    const int chunk = (E + A.nBktB - 1) / A.nBktB;
    const int e0 = bb * chunk, e1 = min(E, e0 + chunk);
    cnt[tid] = 0;
    __syncthreads();
    for (int e = e0 + tid; e < e1; e += 256) atomicAdd(&cnt[A.ei[E + e] >> 8], 1);
    __syncthreads();
    {
        int c = cnt[tid];
        basep[tid] = c ? atomicAdd(&A.bcnt[tid], c) : 0;  // one global atomic per bucket/block
        cnt[tid] = 0;
    }
    __syncthreads();
    for (int e = e0 + tid; e < e1; e += 256) {
        int dst = A.ei[E + e], src = A.ei[e];
        int bkt = dst >> 8;
        int p = basep[bkt] + atomicAdd(&cnt[bkt], 1);
        if (p < A.cap) A.bbuf[(size_t)bkt * A.cap + p] = make_int2(dst, src);
    }
}

// ---------------- part2: per-bucket degree count (LDS), coalesced deg write ----------------
__global__ __launch_bounds__(256) void part2_kernel(const int2* __restrict__ bbuf,
                                                    const int* __restrict__ bcnt,
                                                    int* __restrict__ deg, int cap, int N) {
    __shared__ int ldeg[256];
    const int b = blockIdx.x, t = threadIdx.x;
    ldeg[t] = 0;
    __syncthreads();
    int cnt = bcnt[b];
    const int2* p = bbuf + (size_t)b * cap;
    for (int i = t; i < cnt; i += 256) atomicAdd(&ldeg[p[i].x & 255], 1);
    __syncthreads();
    int node = (b << 8) + t;
    if (node < N) deg[node] = ldeg[t];
}

// ---------------- scan (3-pass hierarchical) ----------------
__global__ __launch_bounds__(256) void scan_pass1(const int* __restrict__ deg,
                                                  int* __restrict__ bsum, int N) {
    __shared__ int red[4];
    int t = threadIdx.x;
    int base = blockIdx.x * 1024 + t * 4;
    int4 v = make_int4(0, 0, 0, 0);
    if (base + 3 < N) v = *(const int4*)(deg + base);
    else {
        if (base + 0 < N) v.x = deg[base + 0];
        if (base + 1 < N) v.y = deg[base + 1];
        if (base + 2 < N) v.z = deg[base + 2];
    }
    int s = v.x + v.y + v.z + v.w;
#pragma unroll
    for (int off = 1; off < 64; off <<= 1) s += __shfl_xor(s, off);
    if ((t & 63) == 0) red[t >> 6] = s;
    __syncthreads();
    if (t == 0) bsum[blockIdx.x] = red[0] + red[1] + red[2] + red[3];
}

__global__ __launch_bounds__(256) void scan_pass2(int* __restrict__ bsum, int nb) {
    __shared__ int sh[256];
    int t = threadIdx.x;
    int v = (t < nb) ? bsum[t] : 0;
    sh[t] = v;
    __syncthreads();
#pragma unroll
    for (int off = 1; off < 256; off <<= 1) {
        int u = (t >= off) ? sh[t - off] : 0;
        __syncthreads();
        sh[t] += u;
        __syncthreads();
    }
    if (t < nb) bsum[t] = sh[t] - v;
}

__global__ __launch_bounds__(256) void scan_pass3(const int* __restrict__ deg,
                                                  const int* __restrict__ bsum,
                                                  int* __restrict__ row_ptr,
                                                  float* __restrict__ cntp1f, int N) {
    __shared__ int sh[256];
    int t = threadIdx.x;
    int base = blockIdx.x * 1024 + t * 4;
    int4 v = make_int4(0, 0, 0, 0);
    if (base + 3 < N) v = *(const int4*)(deg + base);
    else {
        if (base + 0 < N) v.x = deg[base + 0];
        if (base + 1 < N) v.y = deg[base + 1];
        if (base + 2 < N) v.z = deg[base + 2];
    }
    int s = v.x + v.y + v.z + v.w;
    sh[t] = s;
    __syncthreads();
#pragma unroll
    for (int off = 1; off < 256; off <<= 1) {
        int u = (t >= off) ? sh[t - off] : 0;
        __syncthreads();
        sh[t] += u;
        __syncthreads();
    }
    int pre = sh[t] - s + bsum[blockIdx.x];
    int vv[4] = {v.x, v.y, v.z, v.w};
#pragma unroll
    for (int i = 0; i < 4; ++i) {
        int idx = base + i;
        if (idx < N) {
            row_ptr[idx] = pre;
            cntp1f[idx] = (float)(vv[i] + 1);
            pre += vv[i];
            if (idx == N - 1) row_ptr[N] = pre;
        }
    }
}

// ---------------- part3: per-bucket scatter via LDS cursors (holds absolute addrs) ---------
__global__ __launch_bounds__(256) void part3_kernel(const int2* __restrict__ bbuf,
                                                    const int* __restrict__ bcnt,
                                                    const int* __restrict__ row_ptr,
                                                    int* __restrict__ colarr, int cap, int N) {
    __shared__ int lcur[256];
    const int b = blockIdx.x, t = threadIdx.x;
    int node = (b << 8) + t;
    lcur[t] = (node < N) ? row_ptr[node] : 0;
    __syncthreads();
    int cnt = bcnt[b];
    const int2* p = bbuf + (size_t)b * cap;
    for (int i = t; i < cnt; i += 256) {
        int2 e = p[i];
        int addr = atomicAdd(&lcur[e.x & 255], 1);  // LDS returning atomic: cheap
        colarr[addr] = e.y;
    }
}

// ---------------- node GEMM: Y[N, ldc] = X[N,128] @ Wt^T + epilogue (MFMA fp16) ------------
__global__ __launch_bounds__(256) void gemm_node(const f16_t* __restrict__ X,
                                                 const f16_t* __restrict__ Wt,
                                                 const float* __restrict__ bias,
                                                 const float* __restrict__ bias2,
                                                 const float* __restrict__ rowscale,
                                                 f16_t* __restrict__ Y, int N, int ldc,
                                                 int relu_flag) {
    const int coloff = blockIdx.y * 128;
    __shared__ f16_t sX[128 * 128];
    __shared__ f16_t sW[128 * 128];
    const int tid = threadIdx.x;
    const int row0 = blockIdx.x * 128;
#pragma unroll
    for (int it = 0; it < 8; ++it) {
        int idx = tid + it * 256;
        int r = idx >> 4, c8 = idx & 15;
        int gr = row0 + r;
        uint4 v = make_uint4(0, 0, 0, 0);
        if (gr < N) v = *(const uint4*)(X + (size_t)gr * 128 + c8 * 8);
        *(uint4*)(&sX[r * 128 + (c8 ^ (r & 7)) * 8]) = v;
    }
#pragma unroll
    for (int it = 0; it < 8; ++it) {
        int idx = tid + it * 256;
        int r = idx >> 4, c8 = idx & 15;
        uint4 v = *(const uint4*)(Wt + (size_t)(coloff + r) * 128 + c8 * 8);
        *(uint4*)(&sW[r * 128 + (c8 ^ (r & 7)) * 8]) = v;
    }
    __syncthreads();
    const int wave = tid >> 6, lane = tid & 63;
    const int m = lane & 15, q = lane >> 4;
    const int sw = m & 7;
    f32x4 acc[2][8];
#pragma unroll
    for (int rt = 0; rt < 2; ++rt)
#pragma unroll
        for (int t = 0; t < 8; ++t) acc[rt][t] = (f32x4){0.f, 0.f, 0.f, 0.f};
#pragma unroll
    for (int kk = 0; kk < 4; ++kk) {
        const int g = (kk * 4 + q) ^ sw;
        f16x8 a0 = *(const f16x8*)(&sX[(wave * 32 + m) * 128 + g * 8]);
        f16x8 a1 = *(const f16x8*)(&sX[(wave * 32 + 16 + m) * 128 + g * 8]);
#pragma unroll
        for (int t = 0; t < 8; ++t) {
            f16x8 bfr = *(const f16x8*)(&sW[(t * 16 + m) * 128 + g * 8]);
            acc[0][t] = __builtin_amdgcn_mfma_f32_16x16x32_f16(a0, bfr, acc[0][t], 0, 0, 0);
            acc[1][t] = __builtin_amdgcn_mfma_f32_16x16x32_f16(a1, bfr, acc[1][t], 0, 0, 0);
        }
    }
#pragma unroll
    for (int t = 0; t < 8; ++t) {
        int col = coloff + t * 16 + m;
        float bv = bias ? bias[col] : 0.f;
        float b2v = bias2 ? bias2[col] : 0.f;
#pragma unroll
        for (int rt = 0; rt < 2; ++rt) {
#pragma unroll
            for (int j = 0; j < 4; ++j) {
                int r = row0 + wave * 32 + rt * 16 + q * 4 + j;
                if (r < N) {
                    float v = acc[rt][t][j] + bv;
                    if (rowscale) v += rowscale[r] * b2v;
                    if (relu_flag) v = fmaxf(v, 0.f);
                    Y[(size_t)r * ldc + col] = (f16_t)v;
                }
            }
        }
    }
}

// ---------------- edge aggregation: packed fp16, 16 edges in flight per wave ----------------
__global__ __launch_bounds__(256) void gather_kernel(const f16_t* __restrict__ ab,
                                                     const int* __restrict__ row_ptr,
                                                     const int* __restrict__ colarr,
                                                     f16_t* __restrict__ q, int N) {
    int wid = (blockIdx.x * 256 + threadIdx.x) >> 6;
    int lane = threadIdx.x & 63;
    if (wid >= N) return;
    const uint4* abu4 = (const uint4*)ab;
    const int g = lane >> 4, l = lane & 15;
    uint4 A = abu4[(size_t)wid * 32 + l];
    f16x2 a0 = __builtin_bit_cast(f16x2, A.x), a1 = __builtin_bit_cast(f16x2, A.y);
    f16x2 a2 = __builtin_bit_cast(f16x2, A.z), a3 = __builtin_bit_cast(f16x2, A.w);
    f16x2 c0 = (f16x2)0, c1 = (f16x2)0, c2 = (f16x2)0, c3 = (f16x2)0;
    if (g == 0) {  // self loop, counted once
        uint4 B = abu4[(size_t)wid * 32 + 16 + l];
        c0 = relu_add2(a0, __builtin_bit_cast(f16x2, B.x));
        c1 = relu_add2(a1, __builtin_bit_cast(f16x2, B.y));
        c2 = relu_add2(a2, __builtin_bit_cast(f16x2, B.z));
        c3 = relu_add2(a3, __builtin_bit_cast(f16x2, B.w));
    }
    int e0 = row_ptr[wid], e1 = row_ptr[wid + 1];
    int e = e0;
    for (; e + 16 <= e1; e += 16) {
        int s0 = colarr[e + g], s1 = colarr[e + 4 + g];
        int s2 = colarr[e + 8 + g], s3 = colarr[e + 12 + g];
        uint4 B0 = abu4[(size_t)s0 * 32 + 16 + l];
        uint4 B1 = abu4[(size_t)s1 * 32 + 16 + l];
        uint4 B2 = abu4[(size_t)s2 * 32 + 16 + l];
        uint4 B3 = abu4[(size_t)s3 * 32 + 16 + l];
        c0 += relu_add2(a0, __builtin_bit_cast(f16x2, B0.x));
        c1 += relu_add2(a1, __builtin_bit_cast(f16x2, B0.y));
        c2 += relu_add2(a2, __builtin_bit_cast(f16x2, B0.z));
        c3 += relu_add2(a3, __builtin_bit_cast(f16x2, B0.w));
        c0 += relu_add2(a0, __builtin_bit_cast(f16x2, B1.x));
        c1 += relu_add2(a1, __builtin_bit_cast(f16x2, B1.y));
        c2 += relu_add2(a2, __builtin_bit_cast(f16x2, B1.z));
        c3 += relu_add2(a3, __builtin_bit_cast(f16x2, B1.w));
        c0 += relu_add2(a0, __builtin_bit_cast(f16x2, B2.x));
        c1 += relu_add2(a1, __builtin_bit_cast(f16x2, B2.y));
        c2 += relu_add2(a2, __builtin_bit_cast(f16x2, B2.z));
        c3 += relu_add2(a3, __builtin_bit_cast(f16x2, B2.w));
        c0 += relu_add2(a0, __builtin_bit_cast(f16x2, B3.x));
        c1 += relu_add2(a1, __builtin_bit_cast(f16x2, B3.y));
        c2 += relu_add2(a2, __builtin_bit_cast(f16x2, B3.z));
        c3 += relu_add2(a3, __builtin_bit_cast(f16x2, B3.w));
    }
    for (; e < e1; e += 4) {
        int i0 = e + g;
        if (i0 < e1) {
            int src = colarr[i0];
            uint4 B = abu4[(size_t)src * 32 + 16 + l];
            c0 += relu_add2(a0, __builtin_bit_cast(f16x2, B.x));
            c1 += relu_add2(a1, __builtin_bit_cast(f16x2, B.y));
            c2 += relu_add2(a2, __builtin_bit_cast(f16x2, B.z));
            c3 += relu_add2(a3, __builtin_bit_cast(f16x2, B.w));
        }
    }
#pragma unroll
    for (int off = 16; off < 64; off <<= 1) {
        c0 += __builtin_bit_cast(f16x2, __shfl_xor(__builtin_bit_cast(int, c0), off));
        c1 += __builtin_bit_cast(f16x2, __shfl_xor(__builtin_bit_cast(int, c1), off));
        c2 += __builtin_bit_cast(f16x2, __shfl_xor(__builtin_bit_cast(int, c2), off));
        c3 += __builtin_bit_cast(f16x2, __shfl_xor(__builtin_bit_cast(int, c3), off));
    }
    if (g == 0) {
        uint4 o;
        o.x = __builtin_bit_cast(u32, c0);
        o.y = __builtin_bit_cast(u32, c1);
        o.z = __builtin_bit_cast(u32, c2);
        o.w = __builtin_bit_cast(u32, c3);
        ((uint4*)q)[(size_t)wid * 16 + l] = o;
    }
}

// ---------------- pooling ----------------
__global__ __launch_bounds__(256) void pool_kernel(const f16_t* __restrict__ agg,
                                                   const int* __restrict__ batch,
                                                   float* __restrict__ pooled,
                                                   int* __restrict__ cntg, int N) {
    int wid = (blockIdx.x * 256 + threadIdx.x) >> 6;
    int lane = threadIdx.x & 63;
    int n0 = wid * 32;
    if (n0 >= N) return;
    int n1 = min(n0 + 32, N);
    const u32* au = (const u32*)agg;
    int gcur = batch[n0];
    float sx = 0.f, sy = 0.f;
    int cnt = 0;
    for (int n = n0; n < n1; ++n) {
        int g = batch[n];
        if (g != gcur) {
            atomicAdd(&pooled[gcur * 128 + lane * 2], sx);
            atomicAdd(&pooled[gcur * 128 + lane * 2 + 1], sy);
            if (lane == 0) atomicAdd(&cntg[gcur], cnt);
            gcur = g; sx = 0.f; sy = 0.f; cnt = 0;
        }
        u32 v = au[(size_t)n * 64 + lane];
        sx += f16lo(v);
        sy += f16hi(v);
        ++cnt;
    }
    atomicAdd(&pooled[gcur * 128 + lane * 2], sx);
    atomicAdd(&pooled[gcur * 128 + lane * 2 + 1], sy);
    if (lane == 0) atomicAdd(&cntg[gcur], cnt);
}

// ---------------- final ----------------
__global__ __launch_bounds__(256) void final_kernel(const float* __restrict__ pooled,
                                                    const int* __restrict__ cntg,
                                                    const float* __restrict__ out_w,
                                                    const float* __restrict__ out_b,
                                                    float* __restrict__ out, int total) {
    int idx = blockIdx.x * 256 + threadIdx.x;
    if (idx >= total) return;
    int g = idx >> 6, o = idx & 63;
    float c = fmaxf((float)cntg[g], 1.0f);
    float s = 0.f;
#pragma unroll 4
    for (int k = 0; k < 128; ++k) s += pooled[g * 128 + k] * out_w[k * 64 + o];
    out[idx] = s / c + out_b[o];
}

extern "C" void kernel_launch(void* const* d_in, const int* in_sizes, int n_in, void* d_out,
                              int out_size, void* d_ws, size_t ws_size, hipStream_t stream) {
    const float* x = (const float*)d_in[0];
    const int* ei = (const int*)d_in[1];
    const int* batch = (const int*)d_in[3];
    const float* cw[3][6];  // lin_w, lin_b, w1, b1, w2, b2
    for (int l = 0; l < 3; ++l)
        for (int j = 0; j < 6; ++j) cw[l][j] = (const float*)d_in[4 + l * 6 + j];
    const float* out_w = (const float*)d_in[22];
    const float* out_b = (const float*)d_in[23];
    float* out = (float*)d_out;

    const int N = in_sizes[0] / 128;
    const int E = in_sizes[1] / 2;
    const int G = out_size / 64;
    const int nbk = (N + 255) >> 8;          // buckets of 256 nodes
    const int cap = (E + nbk - 1) / nbk + 2048;  // per-bucket capacity (mean + >30 sigma)

    // ---- workspace layout ----
    char* base = (char*)d_ws;
    size_t off = 0;
    auto alloc = [&](size_t b) { size_t o = off; off += (b + 255) & ~(size_t)255; return o; };
    float* pooled = (float*)(base + alloc((size_t)G * 128 * 4));
    int* cntg = (int*)(base + alloc((size_t)G * 4));
    int* bcnt = (int*)(base + alloc(256 * 4));
    const size_t zero_bytes = off;
    int* deg = (int*)(base + alloc((size_t)N * 4));
    int* row_ptr = (int*)(base + alloc((size_t)(N + 1) * 4));
    float* cntp1f = (float*)(base + alloc((size_t)N * 4));
    int* colarr = (int*)(base + alloc((size_t)E * 4));
    int2* bbuf = (int2*)(base + alloc((size_t)nbk * cap * 8));
    int* bsum = (int*)(base + alloc(256 * 4));
    f16_t* xb = (f16_t*)(base + alloc((size_t)N * 128 * 2));  // layer input / agg output
    f16_t* q = (f16_t*)(base + alloc((size_t)N * 128 * 2));   // gather output
    f16_t* ab = (f16_t*)(base + alloc((size_t)N * 256 * 2));  // [a|b]
    f16_t* W12ct = (f16_t*)(base + alloc(3 * 32768 * 2));
    f16_t* W2t = (f16_t*)(base + alloc(3 * 16384 * 2));
    float* bias256c = (float*)(base + alloc(3 * 256 * 4));
    (void)ws_size; (void)n_in;

    hipMemsetAsync(d_ws, 0, zero_bytes, stream);

    // fused prep: convx | prepw x3 | bucketing
    PrepArgs pa;
    pa.x = x; pa.xb = xb; pa.totalx = N * 128;
    pa.ei = ei; pa.E = E;
    pa.bcnt = bcnt; pa.bbuf = bbuf; pa.cap = cap; pa.nBktB = 104;
    for (int l = 0; l < 3; ++l) {
        pa.lin_w[l] = cw[l][0]; pa.lin_b[l] = cw[l][1];
        pa.w1[l] = cw[l][2]; pa.b1[l] = cw[l][3]; pa.w2[l] = cw[l][4];
    }
    pa.W12ct = W12ct; pa.W2t = W2t; pa.bias256c = bias256c;
    const int nConvB = (N * 128 / 4 + 255) / 256;
    prep_kernel<<<nConvB + 3 * 193 + pa.nBktB, 256, 0, stream>>>(pa, nConvB);

    // CSR: bucket counting sort
    part2_kernel<<<nbk, 256, 0, stream>>>(bbuf, bcnt, deg, cap, N);
    const int nb = (N + 1023) / 1024;
    scan_pass1<<<nb, 256, 0, stream>>>(deg, bsum, N);
    scan_pass2<<<1, 256, 0, stream>>>(bsum, nb);
    scan_pass3<<<nb, 256, 0, stream>>>(deg, bsum, row_ptr, cntp1f, N);
    part3_kernel<<<nbk, 256, 0, stream>>>(bbuf, bcnt, row_ptr, colarr, cap, N);

    const int gblocks = (N + 127) / 128;
    auto gemm = [&](const f16_t* X, const f16_t* Wt, const float* bias, const float* bias2,
                    const float* rowscale, f16_t* Y, int ncol, int relu_flag) {
        gemm_node<<<dim3(gblocks, ncol / 128), 256, 0, stream>>>(X, Wt, bias, bias2, rowscale, Y,
                                                                 N, ncol, relu_flag);
    };

    const f16_t* Xin = xb;
    for (int l = 0; l < 3; ++l) {
        gemm(Xin, W12ct + l * 32768, bias256c + l * 256, nullptr, nullptr, ab, 256, 0);
        gather_kernel<<<(N * 64 + 255) / 256, 256, 0, stream>>>(ab, row_ptr, colarr, q, N);
        gemm(q, W2t + l * 16384, nullptr, cw[l][5], cntp1f, xb, 128, 1);
        Xin = xb;
    }

    pool_kernel<<<((N + 31) / 32 * 64 + 255) / 256, 256, 0, stream>>>(Xin, batch, pooled, cntg, N);
    final_kernel<<<(G * 64 + 255) / 256, 256, 0, stream>>>(pooled, cntg, out_w, out_b, out,
                                                           G * 64);
}